// Round 10
// baseline (666.716 us; speedup 1.0000x reference)
//
#include <hip/hip_runtime.h>

typedef _Float16 half_t;
typedef _Float16 half8 __attribute__((ext_vector_type(8)));
typedef _Float16 half4v __attribute__((ext_vector_type(4)));
typedef _Float16 half2v __attribute__((ext_vector_type(2)));
typedef float floatx4 __attribute__((ext_vector_type(4)));

#define TOK 4096
#define DIM 4096
#define S_LEN 1024
#define B_SZ 4
#define HQ_N 32
#define HKV_N 8
#define HD_N 128
#define L_KV 2048
#define NKV 1024
#define NKV2 2048
#define QK_SCALE 0.08838834764831845f
#define LOG2E 1.4426950408889634f

__device__ __forceinline__ void gload_lds16(const void* g, void* l) {
  __builtin_amdgcn_global_load_lds(
      (const __attribute__((address_space(1))) unsigned int*)g,
      (__attribute__((address_space(3))) unsigned int*)l, 16, 0, 0);
}

__device__ __forceinline__ float max3f(float a, float b, float c) {
  return fmaxf(fmaxf(a, b), c);   // fuses to v_max3_f32
}

// ---------------- elementwise f32 -> f16 ----------------
__global__ __launch_bounds__(256) void conv_x_kernel(const float* __restrict__ x,
                                                     half_t* __restrict__ xh) {
  int t = blockIdx.x * 256 + threadIdx.x;
  floatx4 v = *((const floatx4*)x + t);
  half4v o;
  o[0] = (half_t)v[0]; o[1] = (half_t)v[1]; o[2] = (half_t)v[2]; o[3] = (half_t)v[3];
  *((half4v*)xh + t) = o;
}

// ---------------- transpose + convert: out[n][k] = f16(in[k][n]) ----------------
__global__ __launch_bounds__(256) void conv_transpose(const float* __restrict__ in,
                                                      half_t* __restrict__ out,
                                                      int K, int N) {
  __shared__ half_t T[64 * 65];
  const int tid = threadIdx.x;
  const int n0 = blockIdx.x * 64, k0 = blockIdx.y * 64;
  #pragma unroll
  for (int i = 0; i < 16; ++i) {
    int idx = i * 256 + tid;
    int r = idx >> 6, c = idx & 63;
    T[c * 65 + r] = (half_t)in[(size_t)(k0 + r) * N + n0 + c];
  }
  __syncthreads();
  #pragma unroll
  for (int i = 0; i < 16; ++i) {
    int idx = i * 256 + tid;
    int rn = idx >> 6, ck = idx & 63;
    out[(size_t)(n0 + rn) * K + k0 + ck] = T[rn * 65 + ck];
  }
}

// ---------------- 128^2 GEMM (KV projection): C = A * BT^T (green in r2/r3) ----------------
template <typename OT>
__global__ __launch_bounds__(256) void gemm_f16(const half_t* __restrict__ A,
                                                const half_t* __restrict__ BT,
                                                OT* __restrict__ C,
                                                int M, int N, int K) {
  __shared__ half_t As[128 * 32];
  __shared__ half_t Bs[128 * 32];
  const int tid = threadIdx.x;
  const int lane = tid & 63;
  const int w = tid >> 6;
  const int wr = w >> 1, wc = w & 1;
  const int g = lane >> 4, qr = lane & 15;
  const int m0 = blockIdx.y * 128, n0 = blockIdx.x * 128;
  floatx4 acc[4][4] = {};
  const int chb0 = tid & 192;
  for (int k0 = 0; k0 < K; k0 += 32) {
    #pragma unroll
    for (int i = 0; i < 2; ++i) {
      int chb = chb0 + 256 * i;
      int ch = chb + lane;
      int row = ch >> 2, c8 = ch & 3;
      gload_lds16(A + (size_t)(m0 + row) * K + k0 + c8 * 8, (char*)As + chb * 16);
      gload_lds16(BT + (size_t)(n0 + row) * K + k0 + c8 * 8, (char*)Bs + chb * 16);
    }
    __syncthreads();
    half8 af[4], bf[4];
    const int koff = g * 8;
    #pragma unroll
    for (int m = 0; m < 4; ++m)
      af[m] = *(const half8*)&As[(wr * 64 + m * 16 + qr) * 32 + koff];
    #pragma unroll
    for (int n = 0; n < 4; ++n)
      bf[n] = *(const half8*)&Bs[(wc * 64 + n * 16 + qr) * 32 + koff];
    #pragma unroll
    for (int m = 0; m < 4; ++m)
      #pragma unroll
      for (int n = 0; n < 4; ++n)
        acc[m][n] = __builtin_amdgcn_mfma_f32_16x16x32_f16(af[m], bf[n], acc[m][n], 0, 0, 0);
    __syncthreads();
  }
  #pragma unroll
  for (int m = 0; m < 4; ++m) {
    int rb = m0 + wr * 64 + m * 16 + g * 4;
    #pragma unroll
    for (int n = 0; n < 4; ++n) {
      int col = n0 + wc * 64 + n * 16 + qr;
      #pragma unroll
      for (int r = 0; r < 4; ++r)
        C[(size_t)(rb + r) * N + col] = (OT)acc[m][n][r];
    }
  }
}

// ---------------- 256^2 8-phase GEMM (T1..T5): C[M][N] = A[M][K] * BT[N][K]^T ----------------
template <typename OT>
__global__ __launch_bounds__(512) void gemm256(const half_t* __restrict__ A,
                                               const half_t* __restrict__ BT,
                                               OT* __restrict__ C,
                                               int M, int N, int K) {
  __shared__ __align__(16) char smem[131072];   // A dbuf 64K | B dbuf 64K
  const int tid = threadIdx.x;
  const int lane = tid & 63, w = tid >> 6;
  const int g = lane >> 4, qr = lane & 15;
  const int wm = w >> 2, wn = w & 3;
  const int nbx = N >> 8;
  const int nwg = gridDim.x;
  const int cpx = nwg >> 3;
  const int bid = ((int)blockIdx.x & 7) * cpx + ((int)blockIdx.x >> 3);
  const int bx = bid % nbx, by = bid / nbx;
  const int m0 = by << 8, n0 = bx << 8;
  const int NT = K >> 6;

  const int ch0 = tid, ch1 = tid + 512;
  const int sr0 = ch0 >> 3, sc0 = (ch0 & 7) ^ (sr0 & 7);
  const int sr1 = ch1 >> 3, sc1 = (ch1 & 7) ^ (sr1 & 7);
  const size_t so0 = (size_t)sr0 * K + sc0 * 8;
  const size_t so1 = (size_t)sr1 * K + sc1 * 8;
  const int wb = (w * 64) * 16;
  const half_t* Ab = A + (size_t)m0 * K;
  const half_t* Bb = BT + (size_t)n0 * K;

#define G_STAGE(gsrc, ldst)                                   \
  do {                                                        \
    gload_lds16((gsrc) + so0, (char*)(ldst) + wb);            \
    gload_lds16((gsrc) + so1, (char*)(ldst) + wb + 8192);     \
  } while (0)

#define FRAG(base, row, kb) \
  (*(const half8*)((base) + ((((row) * 128) + (kb)) ^ (((row) & 7) << 4))))

  G_STAGE(Ab, smem);                               // t0.A0
  G_STAGE(Ab + (size_t)128 * K, smem + 16384);     // t0.A1
  G_STAGE(Bb, smem + 65536);                       // t0.B0
  G_STAGE(Bb + (size_t)128 * K, smem + 81920);     // t0.B1
  G_STAGE(Ab + 64, smem + 32768);                  // t1.A0
  G_STAGE(Bb + 64, smem + 98304);                  // t1.B0
  asm volatile("s_waitcnt vmcnt(4)" ::: "memory");
  __builtin_amdgcn_s_barrier();

  floatx4 acc[8][4] = {};
  half8 aF[4][2], bF0[2][2], bF1[2][2];

#define MFMA_Q(mh, nh, BF)                                                     \
  do {                                                                         \
    __builtin_amdgcn_s_setprio(1);                                             \
    _Pragma("unroll") for (int mf = 0; mf < 4; ++mf)                           \
    _Pragma("unroll") for (int nf = 0; nf < 2; ++nf)                           \
    _Pragma("unroll") for (int kk = 0; kk < 2; ++kk)                           \
      acc[(mh)*4 + mf][(nh)*2 + nf] = __builtin_amdgcn_mfma_f32_16x16x32_f16(  \
          aF[mf][kk], BF[nf][kk], acc[(mh)*4 + mf][(nh)*2 + nf], 0, 0, 0);     \
    __builtin_amdgcn_s_setprio(0);                                             \
  } while (0)

  for (int t = 0; t < NT; ++t) {
    const char* Ac = smem + ((t & 1) ? 32768 : 0);
    const char* Bc = smem + 65536 + ((t & 1) ? 32768 : 0);
    char* An = smem + ((t & 1) ? 0 : 32768);
    char* Bn = smem + 65536 + ((t & 1) ? 0 : 32768);
    const int t1 = (t + 1 < NT) ? t + 1 : NT - 1;
    const int t2 = (t + 2 < NT) ? t + 2 : NT - 1;
    // phase 0: read aF(mh=0), bF0; stage (t+1).A1
    #pragma unroll
    for (int mf = 0; mf < 4; ++mf)
      #pragma unroll
      for (int kk = 0; kk < 2; ++kk)
        aF[mf][kk] = FRAG(Ac, wm * 128 + mf * 16 + qr, kk * 64 + g * 16);
    #pragma unroll
    for (int nf = 0; nf < 2; ++nf)
      #pragma unroll
      for (int kk = 0; kk < 2; ++kk)
        bF0[nf][kk] = FRAG(Bc, wn * 64 + nf * 16 + qr, kk * 64 + g * 16);
    G_STAGE(Ab + (size_t)128 * K + t1 * 64, An + 16384);
    __builtin_amdgcn_s_barrier();
    asm volatile("s_waitcnt lgkmcnt(0)" ::: "memory");
    MFMA_Q(0, 0, bF0);
    __builtin_amdgcn_s_barrier();
    // phase 1: read bF1; stage (t+1).B1
    #pragma unroll
    for (int nf = 0; nf < 2; ++nf)
      #pragma unroll
      for (int kk = 0; kk < 2; ++kk)
        bF1[nf][kk] = FRAG(Bc, wn * 64 + 32 + nf * 16 + qr, kk * 64 + g * 16);
    G_STAGE(Bb + (size_t)128 * K + t1 * 64, Bn + 16384);
    __builtin_amdgcn_s_barrier();
    asm volatile("s_waitcnt lgkmcnt(0)" ::: "memory");
    MFMA_Q(0, 1, bF1);
    __builtin_amdgcn_s_barrier();
    // phase 2: read aF(mh=1)
    #pragma unroll
    for (int mf = 0; mf < 4; ++mf)
      #pragma unroll
      for (int kk = 0; kk < 2; ++kk)
        aF[mf][kk] = FRAG(Ac, wm * 128 + 64 + mf * 16 + qr, kk * 64 + g * 16);
    __builtin_amdgcn_s_barrier();
    asm volatile("s_waitcnt lgkmcnt(0)" ::: "memory");
    MFMA_Q(1, 1, bF1);
    __builtin_amdgcn_s_barrier();
    // phase 3: stage (t+2).A0/B0 into cur-parity buf; counted vmcnt
    G_STAGE(Ab + (size_t)t2 * 64, (char*)Ac);
    G_STAGE(Bb + (size_t)t2 * 64, (char*)Bc);
    __builtin_amdgcn_s_barrier();
    MFMA_Q(1, 0, bF0);
    asm volatile("s_waitcnt vmcnt(4)" ::: "memory");
    __builtin_amdgcn_s_barrier();
  }
  #pragma unroll
  for (int mh = 0; mh < 2; ++mh)
    #pragma unroll
    for (int mf = 0; mf < 4; ++mf) {
      const int rb = m0 + wm * 128 + mh * 64 + mf * 16 + g * 4;
      #pragma unroll
      for (int nh = 0; nh < 2; ++nh)
        #pragma unroll
        for (int nf = 0; nf < 2; ++nf) {
          const int col = n0 + wn * 64 + nh * 32 + nf * 16 + qr;
          floatx4 v = acc[mh * 4 + mf][nh * 2 + nf];
          #pragma unroll
          for (int r = 0; r < 4; ++r)
            C[(size_t)(rb + r) * N + col] = (OT)v[r];
        }
    }
#undef G_STAGE
#undef FRAG
#undef MFMA_Q
}

// ---------------- pack q: rope + scale*log2e -> [B][HQ][S][HD] f16 ----------------
__global__ __launch_bounds__(256) void pack_q_kernel(const half_t* __restrict__ qf,
                                                     const float* __restrict__ cosT,
                                                     const float* __restrict__ sinT,
                                                     half_t* __restrict__ qh) {
  int t = blockIdx.x * 256 + threadIdx.x;
  int j = t & 63;
  int hq = (t >> 6) & 31;
  int tok = t >> 11;
  int s = tok & 1023;
  int b = tok >> 10;
  const half_t* src = qf + (size_t)tok * DIM + hq * HD_N + 2 * j;
  float xr = (float)src[0], xi = (float)src[1];
  float c = cosT[s * 64 + j], sn = sinT[s * 64 + j];
  const float QS2 = QK_SCALE * LOG2E;   // exp2-domain scores
  half2v o;
  o[0] = (half_t)((xr * c - xi * sn) * QS2);
  o[1] = (half_t)((xr * sn + xi * c) * QS2);
  *(half2v*)(qh + ((size_t)((b * HQ_N + hq) * S_LEN + s)) * HD_N + 2 * j) = o;
}

// ---------------- pack keys from fused kv: cache + rope(new) -> [B][HKV][L][HD] f16 ----------------
__global__ __launch_bounds__(256) void pack_k_kernel(const half_t* __restrict__ kvf,
                                                     const float* __restrict__ cache_k,
                                                     const float* __restrict__ cosT,
                                                     const float* __restrict__ sinT,
                                                     half_t* __restrict__ kh) {
  int t = blockIdx.x * 256 + threadIdx.x;
  int j = t & 63;
  int h = (t >> 6) & 7;
  int pos = (t >> 9) & 2047;
  int b = t >> 20;
  float xr, xi;
  if (pos < 1024) {
    const float* src = cache_k + ((size_t)(b * L_KV + pos) * HKV_N + h) * HD_N + 2 * j;
    xr = src[0]; xi = src[1];
  } else {
    int s = pos - 1024;
    const half_t* src = kvf + (size_t)(b * S_LEN + s) * NKV2 + h * HD_N + 2 * j;
    float r0 = (float)src[0], i0 = (float)src[1];
    float c = cosT[s * 64 + j], sn = sinT[s * 64 + j];
    xr = r0 * c - i0 * sn;
    xi = r0 * sn + i0 * c;
  }
  half2v o; o[0] = (half_t)xr; o[1] = (half_t)xi;
  *(half2v*)(kh + ((size_t)(b * HKV_N + h) * L_KV + pos) * HD_N + 2 * j) = o;
}

// ---------------- pack values transposed from fused kv: -> [B][HKV][HD][L] f16 ----------------
__global__ __launch_bounds__(256) void pack_vt_kernel(const half_t* __restrict__ kvf,
                                                      const float* __restrict__ cache_v,
                                                      half_t* __restrict__ vt) {
  __shared__ half_t T[128 * 129];
  const int tid = threadIdx.x;
  const int blk = blockIdx.x;
  const int pt = blk & 15;
  const int h = (blk >> 4) & 7;
  const int b = blk >> 7;
  const int p0 = pt * 128;
  #pragma unroll
  for (int i = 0; i < 64; ++i) {
    int idx = i * 256 + tid;
    int p = idx >> 7, d = idx & 127;
    int pos = p0 + p;
    float v;
    if (pos < 1024)
      v = cache_v[((size_t)(b * L_KV + pos) * HKV_N + h) * HD_N + d];
    else
      v = (float)kvf[(size_t)(b * S_LEN + (pos - 1024)) * NKV2 + NKV + h * HD_N + d];
    T[d * 129 + p] = (half_t)v;
  }
  __syncthreads();
  #pragma unroll
  for (int i = 0; i < 64; ++i) {
    int idx = i * 256 + tid;
    int d = idx >> 7, p = idx & 127;
    vt[((size_t)(b * HKV_N + h) * HD_N + d) * L_KV + p0 + p] = T[d * 129 + p];
  }
}

// ---------------- flash attention: QBLK=128 (2 q-sets/wave), exp2 softmax, dbuf staging ----------------
// Grid: (HQ, S/128, B) -- qt in blockIdx.y for KV L2 locality (same-x -> same XCD).
// LDS map (bytes): K tiles [2][16384] @0 | V tiles [2][16384] @32768 | P [4][2304] @65536
__global__ __launch_bounds__(256, 2) void attn_kernel(const half_t* __restrict__ qh,
                                                      const half_t* __restrict__ kh,
                                                      const half_t* __restrict__ vt,
                                                      half_t* __restrict__ ah) {
  __shared__ __align__(16) char smem[74752];
  const int tid = threadIdx.x;
  const int lane = tid & 63, w = tid >> 6;
  const int g = lane >> 4, qr = lane & 15;
  const int hq = blockIdx.x, qt = blockIdx.y, b = blockIdx.z;
  const int hkv = hq >> 2;
  const half_t* qbase =
      qh + ((size_t)((b * HQ_N + hq) * S_LEN) + qt * 128 + w * 16 + qr) * HD_N;
  half8 qfA[4], qfB[4];
  #pragma unroll
  for (int c = 0; c < 4; ++c) {
    qfA[c] = *(const half8*)(qbase + g * 8 + c * 32);
    qfB[c] = *(const half8*)(qbase + (size_t)64 * HD_N + g * 8 + c * 32);
  }
  floatx4 accA[8] = {}, accB[8] = {};
  float mA = -1e30f, lA = 0.f, mB = -1e30f, lB = 0.f;
  const half_t* kg = kh + (size_t)(b * HKV_N + hkv) * L_KV * HD_N;
  const half_t* vg = vt + (size_t)(b * HKV_N + hkv) * HD_N * L_KV;

  const int sw = (qr & 7) << 4;
  const char* kqkP[4];
  #pragma unroll
  for (int c = 0; c < 4; ++c) kqkP[c] = smem + qr * 256 + ((g * 16 + c * 64) ^ sw);
  const char* vP[2];
  #pragma unroll
  for (int kc = 0; kc < 2; ++kc)
    vP[kc] = smem + 32768 + qr * 128 + ((kc * 64 + g * 16) ^ sw);
  char* pwP = smem + 65536 + w * 2304 + qr * 144 + g * 8;
  const char* prP = smem + 65536 + w * 2304 + qr * 144 + g * 16;

  const int r0 = tid >> 4;
  const int c8k = (tid & 15) ^ (r0 & 7);
  const half_t* kp[4];
  #pragma unroll
  for (int j = 0; j < 4; ++j) kp[j] = kg + (size_t)(r0 + 16 * j) * HD_N + c8k * 8;
  const int d0v = tid >> 3;
  const int p8v = (tid & 7) ^ (d0v & 7);
  const half_t* vp[4];
  #pragma unroll
  for (int j = 0; j < 4; ++j) vp[j] = vg + (size_t)(d0v + 32 * j) * L_KV + p8v * 8;
  const int ldsb = (tid & 192) * 16;

#define ISSUE_STAGE(NKB)                                                     \
  do {                                                                       \
    _Pragma("unroll") for (int j2 = 0; j2 < 4; ++j2)                         \
      gload_lds16(kp[j2], smem + (NKB) + ldsb + j2 * 4096);                  \
    _Pragma("unroll") for (int j2 = 0; j2 < 4; ++j2)                         \
      gload_lds16(vp[j2], smem + 32768 + (NKB) + ldsb + j2 * 4096);          \
    _Pragma("unroll") for (int j2 = 0; j2 < 4; ++j2) {                       \
      kp[j2] += 8192; vp[j2] += 64;                                          \
    }                                                                        \
  } while (0)

#define QKT(QF, SC, KB)                                                        \
  do {                                                                         \
    __builtin_amdgcn_s_setprio(1);                                             \
    _Pragma("unroll") for (int ts = 0; ts < 4; ++ts) {                         \
      floatx4 tq = {0.f, 0.f, 0.f, 0.f};                                       \
      _Pragma("unroll") for (int c = 0; c < 4; ++c)                            \
        tq = __builtin_amdgcn_mfma_f32_16x16x32_f16(                           \
            *(const half8*)(kqkP[c] + (KB) + ts * 4096), QF[c], tq, 0, 0, 0);  \
      SC[ts*4+0]=tq[0]; SC[ts*4+1]=tq[1]; SC[ts*4+2]=tq[2]; SC[ts*4+3]=tq[3];  \
    }                                                                          \
    __builtin_amdgcn_s_setprio(0);                                             \
  } while (0)

#define SOFTPV(SC, ACC, MR, LR, KB)                                            \
  do {                                                                         \
    float pmax = fmaxf(                                                        \
        max3f(max3f(SC[0], SC[1], SC[2]), max3f(SC[3], SC[4], SC[5]),          \
              max3f(SC[6], SC[7], SC[8])),                                     \
        max3f(max3f(SC[9], SC[10], SC[11]), max3f(SC[12], SC[13], SC[14]),     \
              SC[15]));                                                        \
    pmax = fmaxf(pmax, __shfl_xor(pmax, 16, 64));                              \
    pmax = fmaxf(pmax, __shfl_xor(pmax, 32, 64));                              \
    const bool skip = __all(pmax - MR <= 8.f);                                 \
    const float mnew = skip ? MR : fmaxf(MR, pmax);                            \
    float rs = 0.f;                                                            \
    _Pragma("unroll") for (int j = 0; j < 16; ++j) {                           \
      float p;                                                                 \
      asm("v_exp_f32 %0, %1" : "=v"(p) : "v"(SC[j] - mnew));                   \
      SC[j] = p; rs += p;                                                      \
    }                                                                          \
    rs += __shfl_xor(rs, 16, 64);                                              \
    rs += __shfl_xor(rs, 32, 64);                                              \
    if (skip) {                                                                \
      LR += rs;                                                                \
    } else {                                                                   \
      float scl;                                                               \
      asm("v_exp_f32 %0, %1" : "=v"(scl) : "v"(MR - mnew));                    \
      LR = LR * scl + rs;                                                      \
      float f0 = __shfl(scl, g * 4 + 0, 64), f1 = __shfl(scl, g * 4 + 1, 64);  \
      float f2 = __shfl(scl, g * 4 + 2, 64), f3 = __shfl(scl, g * 4 + 3, 64);  \
      _Pragma("unroll") for (int n = 0; n < 8; ++n) {                          \
        ACC[n][0] *= f0; ACC[n][1] *= f1; ACC[n][2] *= f2; ACC[n][3] *= f3;    \
      }                                                                        \
      MR = mnew;                                                               \
    }                                                                          \
    _Pragma("unroll") for (int ts = 0; ts < 4; ++ts) {                         \
      half2v lo = __builtin_bit_cast(                                          \
          half2v, __builtin_amdgcn_cvt_pkrtz(SC[ts * 4 + 0], SC[ts * 4 + 1])); \
      half2v hi = __builtin_bit_cast(                                          \
          half2v, __builtin_amdgcn_cvt_pkrtz(SC[ts * 4 + 2], SC[ts * 4 + 3])); \
      *(half4v*)(pwP + ts * 32) = __builtin_shufflevector(lo, hi, 0, 1, 2, 3); \
    }                                                                          \
    __builtin_amdgcn_s_setprio(1);                                             \
    _Pragma("unroll") for (int kc = 0; kc < 2; ++kc) {                         \
      half8 pf = *(const half8*)(prP + kc * 64);                               \
      _Pragma("unroll") for (int n = 0; n < 8; ++n)                            \
        ACC[n] = __builtin_amdgcn_mfma_f32_16x16x32_f16(                       \
            pf, *(const half8*)(vP[kc] + (KB) + n * 2048), ACC[n], 0, 0, 0);   \
    }                                                                          \
    __builtin_amdgcn_s_setprio(0);                                             \
  } while (0)

#define COMPUTE2(KB)                       \
  do {                                     \
    float scA[16], scB[16];                \
    QKT(qfA, scA, KB);                     \
    QKT(qfB, scB, KB);                     \
    SOFTPV(scA, accA, mA, lA, KB);         \
    SOFTPV(scB, accB, mB, lB, KB);         \
  } while (0)

#define ENDBAR                                          \
  do {                                                  \
    asm volatile("s_waitcnt vmcnt(0)" ::: "memory");    \
    __builtin_amdgcn_s_barrier();                       \
  } while (0)

  ISSUE_STAGE(0);
  ENDBAR;
  for (int it = 0; it < 15; ++it) {
    ISSUE_STAGE(16384); COMPUTE2(0);     ENDBAR;
    ISSUE_STAGE(0);     COMPUTE2(16384); ENDBAR;
  }
  ISSUE_STAGE(16384); COMPUTE2(0); ENDBAR;
  COMPUTE2(16384);

#define WRITE_OUT(ACC, LR, SOFF)                                            \
  do {                                                                      \
    float il0 = 1.f / __shfl(LR, g * 4 + 0, 64);                            \
    float il1 = 1.f / __shfl(LR, g * 4 + 1, 64);                            \
    float il2 = 1.f / __shfl(LR, g * 4 + 2, 64);                            \
    float il3 = 1.f / __shfl(LR, g * 4 + 3, 64);                            \
    const int tokb = b * S_LEN + qt * 128 + (SOFF) + w * 16 + g * 4;        \
    _Pragma("unroll") for (int n = 0; n < 8; ++n) {                         \
      const int col = hq * HD_N + n * 16 + qr;                              \
      ah[(size_t)(tokb + 0) * DIM + col] = (half_t)(ACC[n][0] * il0);       \
      ah[(size_t)(tokb + 1) * DIM + col] = (half_t)(ACC[n][1] * il1);       \
      ah[(size_t)(tokb + 2) * DIM + col] = (half_t)(ACC[n][2] * il2);       \
      ah[(size_t)(tokb + 3) * DIM + col] = (half_t)(ACC[n][3] * il3);       \
    }                                                                       \
  } while (0)

  WRITE_OUT(accA, lA, 0);
  WRITE_OUT(accB, lB, 64);
#undef ISSUE_STAGE
#undef QKT
#undef SOFTPV
#undef COMPUTE2
#undef ENDBAR
#undef WRITE_OUT
}

extern "C" void kernel_launch(void* const* d_in, const int* in_sizes, int n_in,
                              void* d_out, int out_size, void* d_ws, size_t ws_size,
                              hipStream_t stream) {
  (void)in_sizes; (void)n_in; (void)out_size; (void)ws_size;
  const float* x = (const float*)d_in[0];
  const float* wq = (const float*)d_in[1];
  const float* wk = (const float*)d_in[2];
  const float* wv = (const float*)d_in[3];
  const float* wo = (const float*)d_in[4];
  const float* fc = (const float*)d_in[5];
  const float* fs = (const float*)d_in[6];
  const float* ck = (const float*)d_in[7];
  const float* cv = (const float*)d_in[8];

  char* ws = (char*)d_ws;
  size_t off = 0;
  auto alloc = [&](size_t bytes) {
    char* p = ws + off;
    off += (bytes + 255) & ~(size_t)255;
    return p;
  };
  half_t* xh    = (half_t*)alloc((size_t)TOK * DIM * 2);       // later qh
  half_t* wqT   = (half_t*)alloc((size_t)DIM * DIM * 2);       // later ah
  half_t* kvT   = (half_t*)alloc((size_t)NKV2 * DIM * 2);
  half_t* qf16  = (half_t*)alloc((size_t)TOK * DIM * 2);       // later woT
  half_t* kvf16 = (half_t*)alloc((size_t)TOK * NKV2 * 2);
  half_t* kh    = (half_t*)alloc((size_t)B_SZ * HKV_N * L_KV * HD_N * 2);
  half_t* vth   = (half_t*)alloc((size_t)B_SZ * HKV_N * HD_N * L_KV * 2);
  half_t* qh    = xh;     // alias: xh dead after kv GEMM
  half_t* ah    = wqT;    // alias: wqT dead after q GEMM
  half_t* woT   = qf16;   // alias: qf16 dead after pack_q

  // 1. convert x to f16
  conv_x_kernel<<<dim3(TOK * DIM / 4 / 256), dim3(256), 0, stream>>>(x, xh);
  // 2. weight transposes
  conv_transpose<<<dim3(DIM / 64, DIM / 64), dim3(256), 0, stream>>>(wq, wqT, DIM, DIM);
  conv_transpose<<<dim3(NKV / 64, DIM / 64), dim3(256), 0, stream>>>(wk, kvT, DIM, NKV);
  conv_transpose<<<dim3(NKV / 64, DIM / 64), dim3(256), 0, stream>>>(wv, kvT + (size_t)NKV * DIM, DIM, NKV);
  // 3. projections: Q via 256^2 (256 blocks = exact round); KV via 128^2 (512 blocks, 2/CU)
  gemm256<half_t><<<dim3((TOK / 256) * (DIM / 256)), dim3(512), 0, stream>>>(xh, wqT, qf16, TOK, DIM, DIM);
  gemm_f16<half_t><<<dim3(NKV2 / 128, TOK / 128), dim3(256), 0, stream>>>(xh, kvT, kvf16, TOK, NKV2, DIM);
  // 4. rope + pack (xh dead after kv GEMM -> qh may overwrite it)
  pack_q_kernel<<<dim3(B_SZ * S_LEN * HQ_N * 64 / 256), dim3(256), 0, stream>>>(qf16, fc, fs, qh);
  pack_k_kernel<<<dim3(B_SZ * L_KV * HKV_N * 64 / 256), dim3(256), 0, stream>>>(kvf16, ck, fc, fs, kh);
  pack_vt_kernel<<<dim3(B_SZ * HKV_N * (L_KV / 128)), dim3(256), 0, stream>>>(kvf16, cv, vth);
  // 5. attention (writes ah = old wqT region); grid (hq, qt, b)
  attn_kernel<<<dim3(HQ_N, S_LEN / 128, B_SZ), dim3(256), 0, stream>>>(qh, kh, vth, ah);
  // 6. wo transpose (into qf16 region, dead after pack_q), then output projection
  conv_transpose<<<dim3(DIM / 64, DIM / 64), dim3(256), 0, stream>>>(wo, woT, DIM, DIM);
  gemm256<float><<<dim3((TOK / 256) * (DIM / 256)), dim3(512), 0, stream>>>(ah, woT, (float*)d_out, TOK, DIM, DIM);
}

// Round 11
// 642.999 us; speedup vs baseline: 1.0369x; 1.0369x over previous
//
#include <hip/hip_runtime.h>

typedef _Float16 half_t;
typedef _Float16 half8 __attribute__((ext_vector_type(8)));
typedef _Float16 half4v __attribute__((ext_vector_type(4)));
typedef _Float16 half2v __attribute__((ext_vector_type(2)));
typedef float floatx4 __attribute__((ext_vector_type(4)));

#define TOK 4096
#define DIM 4096
#define S_LEN 1024
#define B_SZ 4
#define HQ_N 32
#define HKV_N 8
#define HD_N 128
#define L_KV 2048
#define NKV 1024
#define NKV2 2048
#define QK_SCALE 0.08838834764831845f
#define LOG2E 1.4426950408889634f

__device__ __forceinline__ void gload_lds16(const void* g, void* l) {
  __builtin_amdgcn_global_load_lds(
      (const __attribute__((address_space(1))) unsigned int*)g,
      (__attribute__((address_space(3))) unsigned int*)l, 16, 0, 0);
}

__device__ __forceinline__ float max3f(float a, float b, float c) {
  return fmaxf(fmaxf(a, b), c);   // fuses to v_max3_f32
}

// ---------------- elementwise f32 -> f16 ----------------
__global__ __launch_bounds__(256) void conv_x_kernel(const float* __restrict__ x,
                                                     half_t* __restrict__ xh) {
  int t = blockIdx.x * 256 + threadIdx.x;
  floatx4 v = *((const floatx4*)x + t);
  half4v o;
  o[0] = (half_t)v[0]; o[1] = (half_t)v[1]; o[2] = (half_t)v[2]; o[3] = (half_t)v[3];
  *((half4v*)xh + t) = o;
}

// ---------------- transpose + convert: out[n][k] = f16(in[k][n]) ----------------
__global__ __launch_bounds__(256) void conv_transpose(const float* __restrict__ in,
                                                      half_t* __restrict__ out,
                                                      int K, int N) {
  __shared__ half_t T[64 * 65];
  const int tid = threadIdx.x;
  const int n0 = blockIdx.x * 64, k0 = blockIdx.y * 64;
  #pragma unroll
  for (int i = 0; i < 16; ++i) {
    int idx = i * 256 + tid;
    int r = idx >> 6, c = idx & 63;
    T[c * 65 + r] = (half_t)in[(size_t)(k0 + r) * N + n0 + c];
  }
  __syncthreads();
  #pragma unroll
  for (int i = 0; i < 16; ++i) {
    int idx = i * 256 + tid;
    int rn = idx >> 6, ck = idx & 63;
    out[(size_t)(n0 + rn) * K + k0 + ck] = T[rn * 65 + ck];
  }
}

// ---------------- 128^2 GEMM (KV projection): C = A * BT^T ----------------
template <typename OT>
__global__ __launch_bounds__(256) void gemm_f16(const half_t* __restrict__ A,
                                                const half_t* __restrict__ BT,
                                                OT* __restrict__ C,
                                                int M, int N, int K) {
  __shared__ half_t As[128 * 32];
  __shared__ half_t Bs[128 * 32];
  const int tid = threadIdx.x;
  const int lane = tid & 63;
  const int w = tid >> 6;
  const int wr = w >> 1, wc = w & 1;
  const int g = lane >> 4, qr = lane & 15;
  const int m0 = blockIdx.y * 128, n0 = blockIdx.x * 128;
  floatx4 acc[4][4] = {};
  const int chb0 = tid & 192;
  for (int k0 = 0; k0 < K; k0 += 32) {
    #pragma unroll
    for (int i = 0; i < 2; ++i) {
      int chb = chb0 + 256 * i;
      int ch = chb + lane;
      int row = ch >> 2, c8 = ch & 3;
      gload_lds16(A + (size_t)(m0 + row) * K + k0 + c8 * 8, (char*)As + chb * 16);
      gload_lds16(BT + (size_t)(n0 + row) * K + k0 + c8 * 8, (char*)Bs + chb * 16);
    }
    __syncthreads();
    half8 af[4], bf[4];
    const int koff = g * 8;
    #pragma unroll
    for (int m = 0; m < 4; ++m)
      af[m] = *(const half8*)&As[(wr * 64 + m * 16 + qr) * 32 + koff];
    #pragma unroll
    for (int n = 0; n < 4; ++n)
      bf[n] = *(const half8*)&Bs[(wc * 64 + n * 16 + qr) * 32 + koff];
    #pragma unroll
    for (int m = 0; m < 4; ++m)
      #pragma unroll
      for (int n = 0; n < 4; ++n)
        acc[m][n] = __builtin_amdgcn_mfma_f32_16x16x32_f16(af[m], bf[n], acc[m][n], 0, 0, 0);
    __syncthreads();
  }
  #pragma unroll
  for (int m = 0; m < 4; ++m) {
    int rb = m0 + wr * 64 + m * 16 + g * 4;
    #pragma unroll
    for (int n = 0; n < 4; ++n) {
      int col = n0 + wc * 64 + n * 16 + qr;
      #pragma unroll
      for (int r = 0; r < 4; ++r)
        C[(size_t)(rb + r) * N + col] = (OT)acc[m][n][r];
    }
  }
}

// ---------------- 256^2 8-phase GEMM (T1..T5): C[M][N] = A[M][K] * BT[N][K]^T ----------------
template <typename OT>
__global__ __launch_bounds__(512) void gemm256(const half_t* __restrict__ A,
                                               const half_t* __restrict__ BT,
                                               OT* __restrict__ C,
                                               int M, int N, int K) {
  __shared__ __align__(16) char smem[131072];   // A dbuf 64K | B dbuf 64K
  const int tid = threadIdx.x;
  const int lane = tid & 63, w = tid >> 6;
  const int g = lane >> 4, qr = lane & 15;
  const int wm = w >> 2, wn = w & 3;
  const int nbx = N >> 8;
  const int nwg = gridDim.x;
  const int cpx = nwg >> 3;
  const int bid = ((int)blockIdx.x & 7) * cpx + ((int)blockIdx.x >> 3);
  const int bx = bid % nbx, by = bid / nbx;
  const int m0 = by << 8, n0 = bx << 8;
  const int NT = K >> 6;

  const int ch0 = tid, ch1 = tid + 512;
  const int sr0 = ch0 >> 3, sc0 = (ch0 & 7) ^ (sr0 & 7);
  const int sr1 = ch1 >> 3, sc1 = (ch1 & 7) ^ (sr1 & 7);
  const size_t so0 = (size_t)sr0 * K + sc0 * 8;
  const size_t so1 = (size_t)sr1 * K + sc1 * 8;
  const int wb = (w * 64) * 16;
  const half_t* Ab = A + (size_t)m0 * K;
  const half_t* Bb = BT + (size_t)n0 * K;

#define G_STAGE(gsrc, ldst)                                   \
  do {                                                        \
    gload_lds16((gsrc) + so0, (char*)(ldst) + wb);            \
    gload_lds16((gsrc) + so1, (char*)(ldst) + wb + 8192);     \
  } while (0)

#define FRAG(base, row, kb) \
  (*(const half8*)((base) + ((((row) * 128) + (kb)) ^ (((row) & 7) << 4))))

  G_STAGE(Ab, smem);                               // t0.A0
  G_STAGE(Ab + (size_t)128 * K, smem + 16384);     // t0.A1
  G_STAGE(Bb, smem + 65536);                       // t0.B0
  G_STAGE(Bb + (size_t)128 * K, smem + 81920);     // t0.B1
  G_STAGE(Ab + 64, smem + 32768);                  // t1.A0
  G_STAGE(Bb + 64, smem + 98304);                  // t1.B0
  asm volatile("s_waitcnt vmcnt(4)" ::: "memory");
  __builtin_amdgcn_s_barrier();

  floatx4 acc[8][4] = {};
  half8 aF[4][2], bF0[2][2], bF1[2][2];

#define MFMA_Q(mh, nh, BF)                                                     \
  do {                                                                         \
    __builtin_amdgcn_s_setprio(1);                                             \
    _Pragma("unroll") for (int mf = 0; mf < 4; ++mf)                           \
    _Pragma("unroll") for (int nf = 0; nf < 2; ++nf)                           \
    _Pragma("unroll") for (int kk = 0; kk < 2; ++kk)                           \
      acc[(mh)*4 + mf][(nh)*2 + nf] = __builtin_amdgcn_mfma_f32_16x16x32_f16(  \
          aF[mf][kk], BF[nf][kk], acc[(mh)*4 + mf][(nh)*2 + nf], 0, 0, 0);     \
    __builtin_amdgcn_s_setprio(0);                                             \
  } while (0)

  for (int t = 0; t < NT; ++t) {
    const char* Ac = smem + ((t & 1) ? 32768 : 0);
    const char* Bc = smem + 65536 + ((t & 1) ? 32768 : 0);
    char* An = smem + ((t & 1) ? 0 : 32768);
    char* Bn = smem + 65536 + ((t & 1) ? 0 : 32768);
    const int t1 = (t + 1 < NT) ? t + 1 : NT - 1;
    const int t2 = (t + 2 < NT) ? t + 2 : NT - 1;
    // phase 0: read aF(mh=0), bF0; stage (t+1).A1
    #pragma unroll
    for (int mf = 0; mf < 4; ++mf)
      #pragma unroll
      for (int kk = 0; kk < 2; ++kk)
        aF[mf][kk] = FRAG(Ac, wm * 128 + mf * 16 + qr, kk * 64 + g * 16);
    #pragma unroll
    for (int nf = 0; nf < 2; ++nf)
      #pragma unroll
      for (int kk = 0; kk < 2; ++kk)
        bF0[nf][kk] = FRAG(Bc, wn * 64 + nf * 16 + qr, kk * 64 + g * 16);
    G_STAGE(Ab + (size_t)128 * K + t1 * 64, An + 16384);
    __builtin_amdgcn_s_barrier();
    asm volatile("s_waitcnt lgkmcnt(0)" ::: "memory");
    MFMA_Q(0, 0, bF0);
    __builtin_amdgcn_s_barrier();
    // phase 1: read bF1; stage (t+1).B1
    #pragma unroll
    for (int nf = 0; nf < 2; ++nf)
      #pragma unroll
      for (int kk = 0; kk < 2; ++kk)
        bF1[nf][kk] = FRAG(Bc, wn * 64 + 32 + nf * 16 + qr, kk * 64 + g * 16);
    G_STAGE(Bb + (size_t)128 * K + t1 * 64, Bn + 16384);
    __builtin_amdgcn_s_barrier();
    asm volatile("s_waitcnt lgkmcnt(0)" ::: "memory");
    MFMA_Q(0, 1, bF1);
    __builtin_amdgcn_s_barrier();
    // phase 2: read aF(mh=1)
    #pragma unroll
    for (int mf = 0; mf < 4; ++mf)
      #pragma unroll
      for (int kk = 0; kk < 2; ++kk)
        aF[mf][kk] = FRAG(Ac, wm * 128 + 64 + mf * 16 + qr, kk * 64 + g * 16);
    __builtin_amdgcn_s_barrier();
    asm volatile("s_waitcnt lgkmcnt(0)" ::: "memory");
    MFMA_Q(1, 1, bF1);
    __builtin_amdgcn_s_barrier();
    // phase 3: stage (t+2).A0/B0 into cur-parity buf; counted vmcnt
    G_STAGE(Ab + (size_t)t2 * 64, (char*)Ac);
    G_STAGE(Bb + (size_t)t2 * 64, (char*)Bc);
    __builtin_amdgcn_s_barrier();
    MFMA_Q(1, 0, bF0);
    asm volatile("s_waitcnt vmcnt(4)" ::: "memory");
    __builtin_amdgcn_s_barrier();
  }
  #pragma unroll
  for (int mh = 0; mh < 2; ++mh)
    #pragma unroll
    for (int mf = 0; mf < 4; ++mf) {
      const int rb = m0 + wm * 128 + mh * 64 + mf * 16 + g * 4;
      #pragma unroll
      for (int nh = 0; nh < 2; ++nh)
        #pragma unroll
        for (int nf = 0; nf < 2; ++nf) {
          const int col = n0 + wn * 64 + nh * 32 + nf * 16 + qr;
          floatx4 v = acc[mh * 4 + mf][nh * 2 + nf];
          #pragma unroll
          for (int r = 0; r < 4; ++r)
            C[(size_t)(rb + r) * N + col] = (OT)v[r];
        }
    }
#undef G_STAGE
#undef FRAG
#undef MFMA_Q
}

// ---------------- pack q: rope + scale*log2e -> [B][HQ][S][HD] f16 ----------------
__global__ __launch_bounds__(256) void pack_q_kernel(const half_t* __restrict__ qf,
                                                     const float* __restrict__ cosT,
                                                     const float* __restrict__ sinT,
                                                     half_t* __restrict__ qh) {
  int t = blockIdx.x * 256 + threadIdx.x;
  int j = t & 63;
  int hq = (t >> 6) & 31;
  int tok = t >> 11;
  int s = tok & 1023;
  int b = tok >> 10;
  const half_t* src = qf + (size_t)tok * DIM + hq * HD_N + 2 * j;
  float xr = (float)src[0], xi = (float)src[1];
  float c = cosT[s * 64 + j], sn = sinT[s * 64 + j];
  const float QS2 = QK_SCALE * LOG2E;   // exp2-domain scores
  half2v o;
  o[0] = (half_t)((xr * c - xi * sn) * QS2);
  o[1] = (half_t)((xr * sn + xi * c) * QS2);
  *(half2v*)(qh + ((size_t)((b * HQ_N + hq) * S_LEN + s)) * HD_N + 2 * j) = o;
}

// ---------------- pack keys from fused kv: cache + rope(new) -> [B][HKV][L][HD] f16 ----------------
__global__ __launch_bounds__(256) void pack_k_kernel(const half_t* __restrict__ kvf,
                                                     const float* __restrict__ cache_k,
                                                     const float* __restrict__ cosT,
                                                     const float* __restrict__ sinT,
                                                     half_t* __restrict__ kh) {
  int t = blockIdx.x * 256 + threadIdx.x;
  int j = t & 63;
  int h = (t >> 6) & 7;
  int pos = (t >> 9) & 2047;
  int b = t >> 20;
  float xr, xi;
  if (pos < 1024) {
    const float* src = cache_k + ((size_t)(b * L_KV + pos) * HKV_N + h) * HD_N + 2 * j;
    xr = src[0]; xi = src[1];
  } else {
    int s = pos - 1024;
    const half_t* src = kvf + (size_t)(b * S_LEN + s) * NKV2 + h * HD_N + 2 * j;
    float r0 = (float)src[0], i0 = (float)src[1];
    float c = cosT[s * 64 + j], sn = sinT[s * 64 + j];
    xr = r0 * c - i0 * sn;
    xi = r0 * sn + i0 * c;
  }
  half2v o; o[0] = (half_t)xr; o[1] = (half_t)xi;
  *(half2v*)(kh + ((size_t)(b * HKV_N + h) * L_KV + pos) * HD_N + 2 * j) = o;
}

// ---------------- pack values transposed from fused kv: -> [B][HKV][HD][L] f16 ----------------
__global__ __launch_bounds__(256) void pack_vt_kernel(const half_t* __restrict__ kvf,
                                                      const float* __restrict__ cache_v,
                                                      half_t* __restrict__ vt) {
  __shared__ half_t T[128 * 129];
  const int tid = threadIdx.x;
  const int blk = blockIdx.x;
  const int pt = blk & 15;
  const int h = (blk >> 4) & 7;
  const int b = blk >> 7;
  const int p0 = pt * 128;
  #pragma unroll
  for (int i = 0; i < 64; ++i) {
    int idx = i * 256 + tid;
    int p = idx >> 7, d = idx & 127;
    int pos = p0 + p;
    float v;
    if (pos < 1024)
      v = cache_v[((size_t)(b * L_KV + pos) * HKV_N + h) * HD_N + d];
    else
      v = (float)kvf[(size_t)(b * S_LEN + (pos - 1024)) * NKV2 + NKV + h * HD_N + d];
    T[d * 129 + p] = (half_t)v;
  }
  __syncthreads();
  #pragma unroll
  for (int i = 0; i < 64; ++i) {
    int idx = i * 256 + tid;
    int d = idx >> 7, p = idx & 127;
    vt[((size_t)(b * HKV_N + h) * HD_N + d) * L_KV + p0 + p] = T[d * 129 + p];
  }
}

// ---------------- flash attention: shared K/V fragment reads across q-sets ----------------
// Grid: (HQ, S/128, B). LDS: K[2][16K] @0 | V[2][16K] @32768 | P [4][2304] @65536.
// Dataflow change vs r10: K-fragment loaded once feeds both sets' QK^T MFMAs;
// each set's P pulled to registers right after its softmax (same-wave DS order),
// then V-fragment loaded once feeds both sets' PV MFMAs. LDS reads: 80->48 KB/wave-iter.
__global__ __launch_bounds__(256, 2) void attn_kernel(const half_t* __restrict__ qh,
                                                      const half_t* __restrict__ kh,
                                                      const half_t* __restrict__ vt,
                                                      half_t* __restrict__ ah) {
  __shared__ __align__(16) char smem[74752];
  const int tid = threadIdx.x;
  const int lane = tid & 63, w = tid >> 6;
  const int g = lane >> 4, qr = lane & 15;
  const int hq = blockIdx.x, qt = blockIdx.y, b = blockIdx.z;
  const int hkv = hq >> 2;
  const half_t* qbase =
      qh + ((size_t)((b * HQ_N + hq) * S_LEN) + qt * 128 + w * 16 + qr) * HD_N;
  half8 qfA[4], qfB[4];
  #pragma unroll
  for (int c = 0; c < 4; ++c) {
    qfA[c] = *(const half8*)(qbase + g * 8 + c * 32);
    qfB[c] = *(const half8*)(qbase + (size_t)64 * HD_N + g * 8 + c * 32);
  }
  floatx4 accA[8] = {}, accB[8] = {};
  float mA = -1e30f, lA = 0.f, mB = -1e30f, lB = 0.f;
  const half_t* kg = kh + (size_t)(b * HKV_N + hkv) * L_KV * HD_N;
  const half_t* vg = vt + (size_t)(b * HKV_N + hkv) * HD_N * L_KV;

  const int sw = (qr & 7) << 4;
  const char* kqkP[4];
  #pragma unroll
  for (int c = 0; c < 4; ++c) kqkP[c] = smem + qr * 256 + ((g * 16 + c * 64) ^ sw);
  const char* vP[2];
  #pragma unroll
  for (int kc = 0; kc < 2; ++kc)
    vP[kc] = smem + 32768 + qr * 128 + ((kc * 64 + g * 16) ^ sw);
  char* pwP = smem + 65536 + w * 2304 + qr * 144 + g * 8;
  const char* prP = smem + 65536 + w * 2304 + qr * 144 + g * 16;

  const int r0 = tid >> 4;
  const int c8k = (tid & 15) ^ (r0 & 7);
  const half_t* kp[4];
  #pragma unroll
  for (int j = 0; j < 4; ++j) kp[j] = kg + (size_t)(r0 + 16 * j) * HD_N + c8k * 8;
  const int d0v = tid >> 3;
  const int p8v = (tid & 7) ^ (d0v & 7);
  const half_t* vp[4];
  #pragma unroll
  for (int j = 0; j < 4; ++j) vp[j] = vg + (size_t)(d0v + 32 * j) * L_KV + p8v * 8;
  const int ldsb = (tid & 192) * 16;

#define ISSUE_STAGE(NKB)                                                     \
  do {                                                                       \
    _Pragma("unroll") for (int j2 = 0; j2 < 4; ++j2)                         \
      gload_lds16(kp[j2], smem + (NKB) + ldsb + j2 * 4096);                  \
    _Pragma("unroll") for (int j2 = 0; j2 < 4; ++j2)                         \
      gload_lds16(vp[j2], smem + 32768 + (NKB) + ldsb + j2 * 4096);          \
    _Pragma("unroll") for (int j2 = 0; j2 < 4; ++j2) {                       \
      kp[j2] += 8192; vp[j2] += 64;                                          \
    }                                                                        \
  } while (0)

// QK^T both sets: one K-fragment load feeds 2 MFMAs
#define QKT2(KB)                                                               \
  do {                                                                         \
    __builtin_amdgcn_s_setprio(1);                                             \
    _Pragma("unroll") for (int ts = 0; ts < 4; ++ts) {                         \
      floatx4 tqA = {0.f, 0.f, 0.f, 0.f}, tqB = {0.f, 0.f, 0.f, 0.f};          \
      _Pragma("unroll") for (int c = 0; c < 4; ++c) {                          \
        half8 kfr = *(const half8*)(kqkP[c] + (KB) + ts * 4096);               \
        tqA = __builtin_amdgcn_mfma_f32_16x16x32_f16(kfr, qfA[c], tqA, 0,0,0); \
        tqB = __builtin_amdgcn_mfma_f32_16x16x32_f16(kfr, qfB[c], tqB, 0,0,0); \
      }                                                                        \
      scA[ts*4+0]=tqA[0]; scA[ts*4+1]=tqA[1];                                  \
      scA[ts*4+2]=tqA[2]; scA[ts*4+3]=tqA[3];                                  \
      scB[ts*4+0]=tqB[0]; scB[ts*4+1]=tqB[1];                                  \
      scB[ts*4+2]=tqB[2]; scB[ts*4+3]=tqB[3];                                  \
    }                                                                          \
    __builtin_amdgcn_s_setprio(0);                                             \
  } while (0)

// softmax for one set; ends with P->LDS write and P-fragment readback (same-wave DS order)
#define SOFTMAX(SC, ACC, MR, LR, PF)                                           \
  do {                                                                         \
    float pmax = fmaxf(                                                        \
        max3f(max3f(SC[0], SC[1], SC[2]), max3f(SC[3], SC[4], SC[5]),          \
              max3f(SC[6], SC[7], SC[8])),                                     \
        max3f(max3f(SC[9], SC[10], SC[11]), max3f(SC[12], SC[13], SC[14]),     \
              SC[15]));                                                        \
    pmax = fmaxf(pmax, __shfl_xor(pmax, 16, 64));                              \
    pmax = fmaxf(pmax, __shfl_xor(pmax, 32, 64));                              \
    const bool skip = __all(pmax - MR <= 8.f);                                 \
    const float mnew = skip ? MR : fmaxf(MR, pmax);                            \
    float rs = 0.f;                                                            \
    _Pragma("unroll") for (int j = 0; j < 16; ++j) {                           \
      float p;                                                                 \
      asm("v_exp_f32 %0, %1" : "=v"(p) : "v"(SC[j] - mnew));                   \
      SC[j] = p; rs += p;                                                      \
    }                                                                          \
    rs += __shfl_xor(rs, 16, 64);                                              \
    rs += __shfl_xor(rs, 32, 64);                                              \
    if (skip) {                                                                \
      LR += rs;                                                                \
    } else {                                                                   \
      float scl;                                                               \
      asm("v_exp_f32 %0, %1" : "=v"(scl) : "v"(MR - mnew));                    \
      LR = LR * scl + rs;                                                      \
      float f0 = __shfl(scl, g * 4 + 0, 64), f1 = __shfl(scl, g * 4 + 1, 64);  \
      float f2 = __shfl(scl, g * 4 + 2, 64), f3 = __shfl(scl, g * 4 + 3, 64);  \
      _Pragma("unroll") for (int n = 0; n < 8; ++n) {                          \
        ACC[n][0] *= f0; ACC[n][1] *= f1; ACC[n][2] *= f2; ACC[n][3] *= f3;    \
      }                                                                        \
      MR = mnew;                                                               \
    }                                                                          \
    _Pragma("unroll") for (int ts = 0; ts < 4; ++ts) {                         \
      half2v lo = __builtin_bit_cast(                                          \
          half2v, __builtin_amdgcn_cvt_pkrtz(SC[ts * 4 + 0], SC[ts * 4 + 1])); \
      half2v hi = __builtin_bit_cast(                                          \
          half2v, __builtin_amdgcn_cvt_pkrtz(SC[ts * 4 + 2], SC[ts * 4 + 3])); \
      *(half4v*)(pwP + ts * 32) = __builtin_shufflevector(lo, hi, 0, 1, 2, 3); \
    }                                                                          \
    PF[0] = *(const half8*)(prP);                                              \
    PF[1] = *(const half8*)(prP + 64);                                         \
  } while (0)

// PV both sets: one V-fragment load feeds 2 MFMAs
#define PV2(KB)                                                                \
  do {                                                                         \
    __builtin_amdgcn_s_setprio(1);                                             \
    _Pragma("unroll") for (int kc = 0; kc < 2; ++kc)                           \
      _Pragma("unroll") for (int n = 0; n < 8; ++n) {                          \
        half8 vfr = *(const half8*)(vP[kc] + (KB) + n * 2048);                 \
        accA[n] = __builtin_amdgcn_mfma_f32_16x16x32_f16(pfA[kc], vfr,         \
                                                         accA[n], 0, 0, 0);   \
        accB[n] = __builtin_amdgcn_mfma_f32_16x16x32_f16(pfB[kc], vfr,         \
                                                         accB[n], 0, 0, 0);   \
      }                                                                        \
    __builtin_amdgcn_s_setprio(0);                                             \
  } while (0)

#define COMPUTE2(KB)                          \
  do {                                        \
    float scA[16], scB[16];                   \
    half8 pfA[2], pfB[2];                     \
    QKT2(KB);                                 \
    SOFTMAX(scA, accA, mA, lA, pfA);          \
    SOFTMAX(scB, accB, mB, lB, pfB);          \
    PV2(KB);                                  \
  } while (0)

#define ENDBAR                                          \
  do {                                                  \
    asm volatile("s_waitcnt vmcnt(0)" ::: "memory");    \
    __builtin_amdgcn_s_barrier();                       \
  } while (0)

  ISSUE_STAGE(0);
  ENDBAR;
  for (int it = 0; it < 15; ++it) {
    ISSUE_STAGE(16384); COMPUTE2(0);     ENDBAR;
    ISSUE_STAGE(0);     COMPUTE2(16384); ENDBAR;
  }
  ISSUE_STAGE(16384); COMPUTE2(0); ENDBAR;
  COMPUTE2(16384);

#define WRITE_OUT(ACC, LR, SOFF)                                            \
  do {                                                                      \
    float il0 = 1.f / __shfl(LR, g * 4 + 0, 64);                            \
    float il1 = 1.f / __shfl(LR, g * 4 + 1, 64);                            \
    float il2 = 1.f / __shfl(LR, g * 4 + 2, 64);                            \
    float il3 = 1.f / __shfl(LR, g * 4 + 3, 64);                            \
    const int tokb = b * S_LEN + qt * 128 + (SOFF) + w * 16 + g * 4;        \
    _Pragma("unroll") for (int n = 0; n < 8; ++n) {                         \
      const int col = hq * HD_N + n * 16 + qr;                              \
      ah[(size_t)(tokb + 0) * DIM + col] = (half_t)(ACC[n][0] * il0);       \
      ah[(size_t)(tokb + 1) * DIM + col] = (half_t)(ACC[n][1] * il1);       \
      ah[(size_t)(tokb + 2) * DIM + col] = (half_t)(ACC[n][2] * il2);       \
      ah[(size_t)(tokb + 3) * DIM + col] = (half_t)(ACC[n][3] * il3);       \
    }                                                                       \
  } while (0)

  WRITE_OUT(accA, lA, 0);
  WRITE_OUT(accB, lB, 64);
#undef ISSUE_STAGE
#undef QKT2
#undef SOFTMAX
#undef PV2
#undef COMPUTE2
#undef ENDBAR
#undef WRITE_OUT
}

extern "C" void kernel_launch(void* const* d_in, const int* in_sizes, int n_in,
                              void* d_out, int out_size, void* d_ws, size_t ws_size,
                              hipStream_t stream) {
  (void)in_sizes; (void)n_in; (void)out_size; (void)ws_size;
  const float* x = (const float*)d_in[0];
  const float* wq = (const float*)d_in[1];
  const float* wk = (const float*)d_in[2];
  const float* wv = (const float*)d_in[3];
  const float* wo = (const float*)d_in[4];
  const float* fc = (const float*)d_in[5];
  const float* fs = (const float*)d_in[6];
  const float* ck = (const float*)d_in[7];
  const float* cv = (const float*)d_in[8];

  char* ws = (char*)d_ws;
  size_t off = 0;
  auto alloc = [&](size_t bytes) {
    char* p = ws + off;
    off += (bytes + 255) & ~(size_t)255;
    return p;
  };
  half_t* xh    = (half_t*)alloc((size_t)TOK * DIM * 2);       // later qh
  half_t* wqT   = (half_t*)alloc((size_t)DIM * DIM * 2);       // later ah
  half_t* kvT   = (half_t*)alloc((size_t)NKV2 * DIM * 2);
  half_t* qf16  = (half_t*)alloc((size_t)TOK * DIM * 2);       // later woT
  half_t* kvf16 = (half_t*)alloc((size_t)TOK * NKV2 * 2);
  half_t* kh    = (half_t*)alloc((size_t)B_SZ * HKV_N * L_KV * HD_N * 2);
  half_t* vth   = (half_t*)alloc((size_t)B_SZ * HKV_N * HD_N * L_KV * 2);
  half_t* qh    = xh;     // alias: xh dead after kv GEMM
  half_t* ah    = wqT;    // alias: wqT dead after q GEMM
  half_t* woT   = qf16;   // alias: qf16 dead after pack_q

  // 1. convert x to f16
  conv_x_kernel<<<dim3(TOK * DIM / 4 / 256), dim3(256), 0, stream>>>(x, xh);
  // 2. weight transposes
  conv_transpose<<<dim3(DIM / 64, DIM / 64), dim3(256), 0, stream>>>(wq, wqT, DIM, DIM);
  conv_transpose<<<dim3(NKV / 64, DIM / 64), dim3(256), 0, stream>>>(wk, kvT, DIM, NKV);
  conv_transpose<<<dim3(NKV / 64, DIM / 64), dim3(256), 0, stream>>>(wv, kvT + (size_t)NKV * DIM, DIM, NKV);
  // 3. projections: Q via 256^2 (256 blocks = exact round); KV via 128^2 (512 blocks, 2/CU)
  gemm256<half_t><<<dim3((TOK / 256) * (DIM / 256)), dim3(512), 0, stream>>>(xh, wqT, qf16, TOK, DIM, DIM);
  gemm_f16<half_t><<<dim3(NKV2 / 128, TOK / 128), dim3(256), 0, stream>>>(xh, kvT, kvf16, TOK, NKV2, DIM);
  // 4. rope + pack (xh dead after kv GEMM -> qh may overwrite it)
  pack_q_kernel<<<dim3(B_SZ * S_LEN * HQ_N * 64 / 256), dim3(256), 0, stream>>>(qf16, fc, fs, qh);
  pack_k_kernel<<<dim3(B_SZ * L_KV * HKV_N * 64 / 256), dim3(256), 0, stream>>>(kvf16, ck, fc, fs, kh);
  pack_vt_kernel<<<dim3(B_SZ * HKV_N * (L_KV / 128)), dim3(256), 0, stream>>>(kvf16, cv, vth);
  // 5. attention (writes ah = old wqT region); grid (hq, qt, b)
  attn_kernel<<<dim3(HQ_N, S_LEN / 128, B_SZ), dim3(256), 0, stream>>>(qh, kh, vth, ah);
  // 6. wo transpose (into qf16 region, dead after pack_q), then output projection
  conv_transpose<<<dim3(DIM / 64, DIM / 64), dim3(256), 0, stream>>>(wo, woT, DIM, DIM);
  gemm256<float><<<dim3((TOK / 256) * (DIM / 256)), dim3(512), 0, stream>>>(ah, woT, (float*)d_out, TOK, DIM, DIM);
}

// Round 12
// 637.040 us; speedup vs baseline: 1.0466x; 1.0094x over previous
//
#include <hip/hip_runtime.h>

typedef _Float16 half_t;
typedef _Float16 half8 __attribute__((ext_vector_type(8)));
typedef _Float16 half4v __attribute__((ext_vector_type(4)));
typedef _Float16 half2v __attribute__((ext_vector_type(2)));
typedef float floatx4 __attribute__((ext_vector_type(4)));

#define TOK 4096
#define DIM 4096
#define S_LEN 1024
#define B_SZ 4
#define HQ_N 32
#define HKV_N 8
#define HD_N 128
#define L_KV 2048
#define NKV 1024
#define NKV2 2048
#define QK_SCALE 0.08838834764831845f
#define LOG2E 1.4426950408889634f

__device__ __forceinline__ void gload_lds16(const void* g, void* l) {
  __builtin_amdgcn_global_load_lds(
      (const __attribute__((address_space(1))) unsigned int*)g,
      (__attribute__((address_space(3))) unsigned int*)l, 16, 0, 0);
}

__device__ __forceinline__ float max3f(float a, float b, float c) {
  return fmaxf(fmaxf(a, b), c);   // fuses to v_max3_f32
}

// ---------------- merged prep: 4 weight transposes + x conversion, one dispatch ----------------
// blocks 0..4095: wq->wqT | 4096..5119: wk->kvT | 5120..6143: wv->kvT+NKV*DIM
// 6144..10239: wo->woT | 10240..26623: conv x->xh
__global__ __launch_bounds__(256) void prep_kernel(const float* __restrict__ x,
                                                   const float* __restrict__ wq,
                                                   const float* __restrict__ wk,
                                                   const float* __restrict__ wv,
                                                   const float* __restrict__ wo,
                                                   half_t* __restrict__ xh,
                                                   half_t* __restrict__ wqT,
                                                   half_t* __restrict__ kvT,
                                                   half_t* __restrict__ woT) {
  __shared__ half_t T[64 * 65];
  const int bid = blockIdx.x;
  const int tid = threadIdx.x;
  if (bid >= 10240) {                       // conv_x path
    int t = (bid - 10240) * 256 + tid;
    floatx4 v = *((const floatx4*)x + t);
    half4v o;
    o[0] = (half_t)v[0]; o[1] = (half_t)v[1]; o[2] = (half_t)v[2]; o[3] = (half_t)v[3];
    *((half4v*)xh + t) = o;
    return;
  }
  const float* in; half_t* out; int N; int lb;
  if (bid < 4096)      { in = wq; out = wqT; N = 4096; lb = bid; }
  else if (bid < 5120) { in = wk; out = kvT; N = 1024; lb = bid - 4096; }
  else if (bid < 6144) { in = wv; out = kvT + (size_t)NKV * DIM; N = 1024; lb = bid - 5120; }
  else                 { in = wo; out = woT; N = 4096; lb = bid - 6144; }
  const int nbx = N >> 6;
  const int n0 = (lb % nbx) * 64, k0 = (lb / nbx) * 64;
  #pragma unroll
  for (int i = 0; i < 16; ++i) {
    int idx = i * 256 + tid;
    int r = idx >> 6, c = idx & 63;
    T[c * 65 + r] = (half_t)in[(size_t)(k0 + r) * N + n0 + c];
  }
  __syncthreads();
  #pragma unroll
  for (int i = 0; i < 16; ++i) {
    int idx = i * 256 + tid;
    int rn = idx >> 6, ck = idx & 63;
    out[(size_t)(n0 + rn) * DIM + k0 + ck] = T[rn * 65 + ck];
  }
}

// ---------------- 128^2 GEMM (KV projection): C = A * BT^T ----------------
template <typename OT>
__global__ __launch_bounds__(256) void gemm_f16(const half_t* __restrict__ A,
                                                const half_t* __restrict__ BT,
                                                OT* __restrict__ C,
                                                int M, int N, int K) {
  __shared__ half_t As[128 * 32];
  __shared__ half_t Bs[128 * 32];
  const int tid = threadIdx.x;
  const int lane = tid & 63;
  const int w = tid >> 6;
  const int wr = w >> 1, wc = w & 1;
  const int g = lane >> 4, qr = lane & 15;
  const int m0 = blockIdx.y * 128, n0 = blockIdx.x * 128;
  floatx4 acc[4][4] = {};
  const int chb0 = tid & 192;
  for (int k0 = 0; k0 < K; k0 += 32) {
    #pragma unroll
    for (int i = 0; i < 2; ++i) {
      int chb = chb0 + 256 * i;
      int ch = chb + lane;
      int row = ch >> 2, c8 = ch & 3;
      gload_lds16(A + (size_t)(m0 + row) * K + k0 + c8 * 8, (char*)As + chb * 16);
      gload_lds16(BT + (size_t)(n0 + row) * K + k0 + c8 * 8, (char*)Bs + chb * 16);
    }
    __syncthreads();
    half8 af[4], bf[4];
    const int koff = g * 8;
    #pragma unroll
    for (int m = 0; m < 4; ++m)
      af[m] = *(const half8*)&As[(wr * 64 + m * 16 + qr) * 32 + koff];
    #pragma unroll
    for (int n = 0; n < 4; ++n)
      bf[n] = *(const half8*)&Bs[(wc * 64 + n * 16 + qr) * 32 + koff];
    #pragma unroll
    for (int m = 0; m < 4; ++m)
      #pragma unroll
      for (int n = 0; n < 4; ++n)
        acc[m][n] = __builtin_amdgcn_mfma_f32_16x16x32_f16(af[m], bf[n], acc[m][n], 0, 0, 0);
    __syncthreads();
  }
  #pragma unroll
  for (int m = 0; m < 4; ++m) {
    int rb = m0 + wr * 64 + m * 16 + g * 4;
    #pragma unroll
    for (int n = 0; n < 4; ++n) {
      int col = n0 + wc * 64 + n * 16 + qr;
      #pragma unroll
      for (int r = 0; r < 4; ++r)
        C[(size_t)(rb + r) * N + col] = (OT)acc[m][n][r];
    }
  }
}

// ---------------- 256^2 8-phase GEMM (T1..T5): C[M][N] = A[M][K] * BT[N][K]^T ----------------
template <typename OT>
__global__ __launch_bounds__(512) void gemm256(const half_t* __restrict__ A,
                                               const half_t* __restrict__ BT,
                                               OT* __restrict__ C,
                                               int M, int N, int K) {
  __shared__ __align__(16) char smem[131072];   // A dbuf 64K | B dbuf 64K
  const int tid = threadIdx.x;
  const int lane = tid & 63, w = tid >> 6;
  const int g = lane >> 4, qr = lane & 15;
  const int wm = w >> 2, wn = w & 3;
  const int nbx = N >> 8;
  const int nwg = gridDim.x;
  const int cpx = nwg >> 3;
  const int bid = ((int)blockIdx.x & 7) * cpx + ((int)blockIdx.x >> 3);
  const int bx = bid % nbx, by = bid / nbx;
  const int m0 = by << 8, n0 = bx << 8;
  const int NT = K >> 6;

  const int ch0 = tid, ch1 = tid + 512;
  const int sr0 = ch0 >> 3, sc0 = (ch0 & 7) ^ (sr0 & 7);
  const int sr1 = ch1 >> 3, sc1 = (ch1 & 7) ^ (sr1 & 7);
  const size_t so0 = (size_t)sr0 * K + sc0 * 8;
  const size_t so1 = (size_t)sr1 * K + sc1 * 8;
  const int wb = (w * 64) * 16;
  const half_t* Ab = A + (size_t)m0 * K;
  const half_t* Bb = BT + (size_t)n0 * K;

#define G_STAGE(gsrc, ldst)                                   \
  do {                                                        \
    gload_lds16((gsrc) + so0, (char*)(ldst) + wb);            \
    gload_lds16((gsrc) + so1, (char*)(ldst) + wb + 8192);     \
  } while (0)

#define FRAG(base, row, kb) \
  (*(const half8*)((base) + ((((row) * 128) + (kb)) ^ (((row) & 7) << 4))))

  G_STAGE(Ab, smem);                               // t0.A0
  G_STAGE(Ab + (size_t)128 * K, smem + 16384);     // t0.A1
  G_STAGE(Bb, smem + 65536);                       // t0.B0
  G_STAGE(Bb + (size_t)128 * K, smem + 81920);     // t0.B1
  G_STAGE(Ab + 64, smem + 32768);                  // t1.A0
  G_STAGE(Bb + 64, smem + 98304);                  // t1.B0
  asm volatile("s_waitcnt vmcnt(4)" ::: "memory");
  __builtin_amdgcn_s_barrier();

  floatx4 acc[8][4] = {};
  half8 aF[4][2], bF0[2][2], bF1[2][2];

#define MFMA_Q(mh, nh, BF)                                                     \
  do {                                                                         \
    __builtin_amdgcn_s_setprio(1);                                             \
    _Pragma("unroll") for (int mf = 0; mf < 4; ++mf)                           \
    _Pragma("unroll") for (int nf = 0; nf < 2; ++nf)                           \
    _Pragma("unroll") for (int kk = 0; kk < 2; ++kk)                           \
      acc[(mh)*4 + mf][(nh)*2 + nf] = __builtin_amdgcn_mfma_f32_16x16x32_f16(  \
          aF[mf][kk], BF[nf][kk], acc[(mh)*4 + mf][(nh)*2 + nf], 0, 0, 0);     \
    __builtin_amdgcn_s_setprio(0);                                             \
  } while (0)

  for (int t = 0; t < NT; ++t) {
    const char* Ac = smem + ((t & 1) ? 32768 : 0);
    const char* Bc = smem + 65536 + ((t & 1) ? 32768 : 0);
    char* An = smem + ((t & 1) ? 0 : 32768);
    char* Bn = smem + 65536 + ((t & 1) ? 0 : 32768);
    const int t1 = (t + 1 < NT) ? t + 1 : NT - 1;
    const int t2 = (t + 2 < NT) ? t + 2 : NT - 1;
    // phase 0: read aF(mh=0), bF0; stage (t+1).A1
    #pragma unroll
    for (int mf = 0; mf < 4; ++mf)
      #pragma unroll
      for (int kk = 0; kk < 2; ++kk)
        aF[mf][kk] = FRAG(Ac, wm * 128 + mf * 16 + qr, kk * 64 + g * 16);
    #pragma unroll
    for (int nf = 0; nf < 2; ++nf)
      #pragma unroll
      for (int kk = 0; kk < 2; ++kk)
        bF0[nf][kk] = FRAG(Bc, wn * 64 + nf * 16 + qr, kk * 64 + g * 16);
    G_STAGE(Ab + (size_t)128 * K + t1 * 64, An + 16384);
    __builtin_amdgcn_s_barrier();
    asm volatile("s_waitcnt lgkmcnt(0)" ::: "memory");
    MFMA_Q(0, 0, bF0);
    __builtin_amdgcn_s_barrier();
    // phase 1: read bF1; stage (t+1).B1
    #pragma unroll
    for (int nf = 0; nf < 2; ++nf)
      #pragma unroll
      for (int kk = 0; kk < 2; ++kk)
        bF1[nf][kk] = FRAG(Bc, wn * 64 + 32 + nf * 16 + qr, kk * 64 + g * 16);
    G_STAGE(Bb + (size_t)128 * K + t1 * 64, Bn + 16384);
    __builtin_amdgcn_s_barrier();
    asm volatile("s_waitcnt lgkmcnt(0)" ::: "memory");
    MFMA_Q(0, 1, bF1);
    __builtin_amdgcn_s_barrier();
    // phase 2: read aF(mh=1)
    #pragma unroll
    for (int mf = 0; mf < 4; ++mf)
      #pragma unroll
      for (int kk = 0; kk < 2; ++kk)
        aF[mf][kk] = FRAG(Ac, wm * 128 + 64 + mf * 16 + qr, kk * 64 + g * 16);
    __builtin_amdgcn_s_barrier();
    asm volatile("s_waitcnt lgkmcnt(0)" ::: "memory");
    MFMA_Q(1, 1, bF1);
    __builtin_amdgcn_s_barrier();
    // phase 3: stage (t+2).A0/B0 into cur-parity buf; counted vmcnt
    G_STAGE(Ab + (size_t)t2 * 64, (char*)Ac);
    G_STAGE(Bb + (size_t)t2 * 64, (char*)Bc);
    __builtin_amdgcn_s_barrier();
    MFMA_Q(1, 0, bF0);
    asm volatile("s_waitcnt vmcnt(4)" ::: "memory");
    __builtin_amdgcn_s_barrier();
  }
  #pragma unroll
  for (int mh = 0; mh < 2; ++mh)
    #pragma unroll
    for (int mf = 0; mf < 4; ++mf) {
      const int rb = m0 + wm * 128 + mh * 64 + mf * 16 + g * 4;
      #pragma unroll
      for (int nh = 0; nh < 2; ++nh)
        #pragma unroll
        for (int nf = 0; nf < 2; ++nf) {
          const int col = n0 + wn * 64 + nh * 32 + nf * 16 + qr;
          floatx4 v = acc[mh * 4 + mf][nh * 2 + nf];
          #pragma unroll
          for (int r = 0; r < 4; ++r)
            C[(size_t)(rb + r) * N + col] = (OT)v[r];
        }
    }
#undef G_STAGE
#undef FRAG
#undef MFMA_Q
}

// ---------------- pack q: rope + scale*log2e -> [B][HQ][S][HD] f16 ----------------
__global__ __launch_bounds__(256) void pack_q_kernel(const half_t* __restrict__ qf,
                                                     const float* __restrict__ cosT,
                                                     const float* __restrict__ sinT,
                                                     half_t* __restrict__ qh) {
  int t = blockIdx.x * 256 + threadIdx.x;
  int j = t & 63;
  int hq = (t >> 6) & 31;
  int tok = t >> 11;
  int s = tok & 1023;
  int b = tok >> 10;
  const half_t* src = qf + (size_t)tok * DIM + hq * HD_N + 2 * j;
  float xr = (float)src[0], xi = (float)src[1];
  float c = cosT[s * 64 + j], sn = sinT[s * 64 + j];
  const float QS2 = QK_SCALE * LOG2E;   // exp2-domain scores
  half2v o;
  o[0] = (half_t)((xr * c - xi * sn) * QS2);
  o[1] = (half_t)((xr * sn + xi * c) * QS2);
  *(half2v*)(qh + ((size_t)((b * HQ_N + hq) * S_LEN + s)) * HD_N + 2 * j) = o;
}

// ---------------- pack keys from fused kv: cache + rope(new) -> [B][HKV][L][HD] f16 ----------------
__global__ __launch_bounds__(256) void pack_k_kernel(const half_t* __restrict__ kvf,
                                                     const float* __restrict__ cache_k,
                                                     const float* __restrict__ cosT,
                                                     const float* __restrict__ sinT,
                                                     half_t* __restrict__ kh) {
  int t = blockIdx.x * 256 + threadIdx.x;
  int j = t & 63;
  int h = (t >> 6) & 7;
  int pos = (t >> 9) & 2047;
  int b = t >> 20;
  float xr, xi;
  if (pos < 1024) {
    const float* src = cache_k + ((size_t)(b * L_KV + pos) * HKV_N + h) * HD_N + 2 * j;
    xr = src[0]; xi = src[1];
  } else {
    int s = pos - 1024;
    const half_t* src = kvf + (size_t)(b * S_LEN + s) * NKV2 + h * HD_N + 2 * j;
    float r0 = (float)src[0], i0 = (float)src[1];
    float c = cosT[s * 64 + j], sn = sinT[s * 64 + j];
    xr = r0 * c - i0 * sn;
    xi = r0 * sn + i0 * c;
  }
  half2v o; o[0] = (half_t)xr; o[1] = (half_t)xi;
  *(half2v*)(kh + ((size_t)(b * HKV_N + h) * L_KV + pos) * HD_N + 2 * j) = o;
}

// ---------------- pack values transposed from fused kv: -> [B][HKV][HD][L] f16 ----------------
__global__ __launch_bounds__(256) void pack_vt_kernel(const half_t* __restrict__ kvf,
                                                      const float* __restrict__ cache_v,
                                                      half_t* __restrict__ vt) {
  __shared__ half_t T[128 * 129];
  const int tid = threadIdx.x;
  const int blk = blockIdx.x;
  const int pt = blk & 15;
  const int h = (blk >> 4) & 7;
  const int b = blk >> 7;
  const int p0 = pt * 128;
  #pragma unroll
  for (int i = 0; i < 64; ++i) {
    int idx = i * 256 + tid;
    int p = idx >> 7, d = idx & 127;
    int pos = p0 + p;
    float v;
    if (pos < 1024)
      v = cache_v[((size_t)(b * L_KV + pos) * HKV_N + h) * HD_N + d];
    else
      v = (float)kvf[(size_t)(b * S_LEN + (pos - 1024)) * NKV2 + NKV + h * HD_N + d];
    T[d * 129 + p] = (half_t)v;
  }
  __syncthreads();
  #pragma unroll
  for (int i = 0; i < 64; ++i) {
    int idx = i * 256 + tid;
    int d = idx >> 7, p = idx & 127;
    vt[((size_t)(b * HKV_N + h) * HD_N + d) * L_KV + p0 + p] = T[d * 129 + p];
  }
}

// ---------------- flash attention: shared K/V fragments, conflict-free P layout ----------------
// Grid: (HQ, S/128, B). LDS: K[2][16K] @0 | V[2][16K] @32768 | P [4][2048] @65536.
// P layout now matches the K-tile pattern: 128B rows, byte ^ ((row&7)<<4) swizzle
// (the old 144B-stride layout had 4-8 way bank aliasing on the PV read).
__global__ __launch_bounds__(256, 2) void attn_kernel(const half_t* __restrict__ qh,
                                                      const half_t* __restrict__ kh,
                                                      const half_t* __restrict__ vt,
                                                      half_t* __restrict__ ah) {
  __shared__ __align__(16) char smem[73728];
  const int tid = threadIdx.x;
  const int lane = tid & 63, w = tid >> 6;
  const int g = lane >> 4, qr = lane & 15;
  const int hq = blockIdx.x, qt = blockIdx.y, b = blockIdx.z;
  const int hkv = hq >> 2;
  const half_t* qbase =
      qh + ((size_t)((b * HQ_N + hq) * S_LEN) + qt * 128 + w * 16 + qr) * HD_N;
  half8 qfA[4], qfB[4];
  #pragma unroll
  for (int c = 0; c < 4; ++c) {
    qfA[c] = *(const half8*)(qbase + g * 8 + c * 32);
    qfB[c] = *(const half8*)(qbase + (size_t)64 * HD_N + g * 8 + c * 32);
  }
  floatx4 accA[8] = {}, accB[8] = {};
  float mA = -1e30f, lA = 0.f, mB = -1e30f, lB = 0.f;
  const half_t* kg = kh + (size_t)(b * HKV_N + hkv) * L_KV * HD_N;
  const half_t* vg = vt + (size_t)(b * HKV_N + hkv) * HD_N * L_KV;

  const int sw = (qr & 7) << 4;
  const char* kqkP[4];
  #pragma unroll
  for (int c = 0; c < 4; ++c) kqkP[c] = smem + qr * 256 + ((g * 16 + c * 64) ^ sw);
  const char* vP[2];
  #pragma unroll
  for (int kc = 0; kc < 2; ++kc)
    vP[kc] = smem + 32768 + qr * 128 + ((kc * 64 + g * 16) ^ sw);
  // P buffer: per wave 16 rows x 128B, K-style swizzle; write 8B chunks, read 16B
  char* pB = smem + 65536 + w * 2048 + qr * 128;
  char* pwQ[4];
  #pragma unroll
  for (int ts = 0; ts < 4; ++ts) pwQ[ts] = pB + ((ts * 32 + g * 8) ^ sw);
  const char* prR[2];
  #pragma unroll
  for (int kc = 0; kc < 2; ++kc) prR[kc] = pB + ((kc * 64 + g * 16) ^ sw);

  const int r0 = tid >> 4;
  const int c8k = (tid & 15) ^ (r0 & 7);
  const half_t* kp[4];
  #pragma unroll
  for (int j = 0; j < 4; ++j) kp[j] = kg + (size_t)(r0 + 16 * j) * HD_N + c8k * 8;
  const int d0v = tid >> 3;
  const int p8v = (tid & 7) ^ (d0v & 7);
  const half_t* vp[4];
  #pragma unroll
  for (int j = 0; j < 4; ++j) vp[j] = vg + (size_t)(d0v + 32 * j) * L_KV + p8v * 8;
  const int ldsb = (tid & 192) * 16;

#define ISSUE_STAGE(NKB)                                                     \
  do {                                                                       \
    _Pragma("unroll") for (int j2 = 0; j2 < 4; ++j2)                         \
      gload_lds16(kp[j2], smem + (NKB) + ldsb + j2 * 4096);                  \
    _Pragma("unroll") for (int j2 = 0; j2 < 4; ++j2)                         \
      gload_lds16(vp[j2], smem + 32768 + (NKB) + ldsb + j2 * 4096);          \
    _Pragma("unroll") for (int j2 = 0; j2 < 4; ++j2) {                       \
      kp[j2] += 8192; vp[j2] += 64;                                          \
    }                                                                        \
  } while (0)

// QK^T both sets: one K-fragment load feeds 2 MFMAs
#define QKT2(KB)                                                               \
  do {                                                                         \
    __builtin_amdgcn_s_setprio(1);                                             \
    _Pragma("unroll") for (int ts = 0; ts < 4; ++ts) {                         \
      floatx4 tqA = {0.f, 0.f, 0.f, 0.f}, tqB = {0.f, 0.f, 0.f, 0.f};          \
      _Pragma("unroll") for (int c = 0; c < 4; ++c) {                          \
        half8 kfr = *(const half8*)(kqkP[c] + (KB) + ts * 4096);               \
        tqA = __builtin_amdgcn_mfma_f32_16x16x32_f16(kfr, qfA[c], tqA, 0,0,0); \
        tqB = __builtin_amdgcn_mfma_f32_16x16x32_f16(kfr, qfB[c], tqB, 0,0,0); \
      }                                                                        \
      scA[ts*4+0]=tqA[0]; scA[ts*4+1]=tqA[1];                                  \
      scA[ts*4+2]=tqA[2]; scA[ts*4+3]=tqA[3];                                  \
      scB[ts*4+0]=tqB[0]; scB[ts*4+1]=tqB[1];                                  \
      scB[ts*4+2]=tqB[2]; scB[ts*4+3]=tqB[3];                                  \
    }                                                                          \
    __builtin_amdgcn_s_setprio(0);                                             \
  } while (0)

// softmax for one set; ends with P->LDS write and P-fragment readback (same-wave DS order)
#define SOFTMAX(SC, ACC, MR, LR, PF)                                           \
  do {                                                                         \
    float pmax = fmaxf(                                                        \
        max3f(max3f(SC[0], SC[1], SC[2]), max3f(SC[3], SC[4], SC[5]),          \
              max3f(SC[6], SC[7], SC[8])),                                     \
        max3f(max3f(SC[9], SC[10], SC[11]), max3f(SC[12], SC[13], SC[14]),     \
              SC[15]));                                                        \
    pmax = fmaxf(pmax, __shfl_xor(pmax, 16, 64));                              \
    pmax = fmaxf(pmax, __shfl_xor(pmax, 32, 64));                              \
    const bool skip = __all(pmax - MR <= 8.f);                                 \
    const float mnew = skip ? MR : fmaxf(MR, pmax);                            \
    float rs = 0.f;                                                            \
    _Pragma("unroll") for (int j = 0; j < 16; ++j) {                           \
      float p;                                                                 \
      asm("v_exp_f32 %0, %1" : "=v"(p) : "v"(SC[j] - mnew));                   \
      SC[j] = p; rs += p;                                                      \
    }                                                                          \
    rs += __shfl_xor(rs, 16, 64);                                              \
    rs += __shfl_xor(rs, 32, 64);                                              \
    if (skip) {                                                                \
      LR += rs;                                                                \
    } else {                                                                   \
      float scl;                                                               \
      asm("v_exp_f32 %0, %1" : "=v"(scl) : "v"(MR - mnew));                    \
      LR = LR * scl + rs;                                                      \
      float f0 = __shfl(scl, g * 4 + 0, 64), f1 = __shfl(scl, g * 4 + 1, 64);  \
      float f2 = __shfl(scl, g * 4 + 2, 64), f3 = __shfl(scl, g * 4 + 3, 64);  \
      _Pragma("unroll") for (int n = 0; n < 8; ++n) {                          \
        ACC[n][0] *= f0; ACC[n][1] *= f1; ACC[n][2] *= f2; ACC[n][3] *= f3;    \
      }                                                                        \
      MR = mnew;                                                               \
    }                                                                          \
    _Pragma("unroll") for (int ts = 0; ts < 4; ++ts) {                         \
      half2v lo = __builtin_bit_cast(                                          \
          half2v, __builtin_amdgcn_cvt_pkrtz(SC[ts * 4 + 0], SC[ts * 4 + 1])); \
      half2v hi = __builtin_bit_cast(                                          \
          half2v, __builtin_amdgcn_cvt_pkrtz(SC[ts * 4 + 2], SC[ts * 4 + 3])); \
      *(half4v*)(pwQ[ts]) = __builtin_shufflevector(lo, hi, 0, 1, 2, 3);       \
    }                                                                          \
    PF[0] = *(const half8*)(prR[0]);                                           \
    PF[1] = *(const half8*)(prR[1]);                                           \
  } while (0)

// PV both sets: one V-fragment load feeds 2 MFMAs
#define PV2(KB)                                                                \
  do {                                                                         \
    __builtin_amdgcn_s_setprio(1);                                             \
    _Pragma("unroll") for (int kc = 0; kc < 2; ++kc)                           \
      _Pragma("unroll") for (int n = 0; n < 8; ++n) {                          \
        half8 vfr = *(const half8*)(vP[kc] + (KB) + n * 2048);                 \
        accA[n] = __builtin_amdgcn_mfma_f32_16x16x32_f16(pfA[kc], vfr,         \
                                                         accA[n], 0, 0, 0);   \
        accB[n] = __builtin_amdgcn_mfma_f32_16x16x32_f16(pfB[kc], vfr,         \
                                                         accB[n], 0, 0, 0);   \
      }                                                                        \
    __builtin_amdgcn_s_setprio(0);                                             \
  } while (0)

#define COMPUTE2(KB)                          \
  do {                                        \
    float scA[16], scB[16];                   \
    half8 pfA[2], pfB[2];                     \
    QKT2(KB);                                 \
    SOFTMAX(scA, accA, mA, lA, pfA);          \
    SOFTMAX(scB, accB, mB, lB, pfB);          \
    PV2(KB);                                  \
  } while (0)

#define ENDBAR                                          \
  do {                                                  \
    asm volatile("s_waitcnt vmcnt(0)" ::: "memory");    \
    __builtin_amdgcn_s_barrier();                       \
  } while (0)

  ISSUE_STAGE(0);
  ENDBAR;
  for (int it = 0; it < 15; ++it) {
    ISSUE_STAGE(16384); COMPUTE2(0);     ENDBAR;
    ISSUE_STAGE(0);     COMPUTE2(16384); ENDBAR;
  }
  ISSUE_STAGE(16384); COMPUTE2(0); ENDBAR;
  COMPUTE2(16384);

#define WRITE_OUT(ACC, LR, SOFF)                                            \
  do {                                                                      \
    float il0 = 1.f / __shfl(LR, g * 4 + 0, 64);                            \
    float il1 = 1.f / __shfl(LR, g * 4 + 1, 64);                            \
    float il2 = 1.f / __shfl(LR, g * 4 + 2, 64);                            \
    float il3 = 1.f / __shfl(LR, g * 4 + 3, 64);                            \
    const int tokb = b * S_LEN + qt * 128 + (SOFF) + w * 16 + g * 4;        \
    _Pragma("unroll") for (int n = 0; n < 8; ++n) {                         \
      const int col = hq * HD_N + n * 16 + qr;                              \
      ah[(size_t)(tokb + 0) * DIM + col] = (half_t)(ACC[n][0] * il0);       \
      ah[(size_t)(tokb + 1) * DIM + col] = (half_t)(ACC[n][1] * il1);       \
      ah[(size_t)(tokb + 2) * DIM + col] = (half_t)(ACC[n][2] * il2);       \
      ah[(size_t)(tokb + 3) * DIM + col] = (half_t)(ACC[n][3] * il3);       \
    }                                                                       \
  } while (0)

  WRITE_OUT(accA, lA, 0);
  WRITE_OUT(accB, lB, 64);
#undef ISSUE_STAGE
#undef QKT2
#undef SOFTMAX
#undef PV2
#undef COMPUTE2
#undef ENDBAR
#undef WRITE_OUT
}

extern "C" void kernel_launch(void* const* d_in, const int* in_sizes, int n_in,
                              void* d_out, int out_size, void* d_ws, size_t ws_size,
                              hipStream_t stream) {
  (void)in_sizes; (void)n_in; (void)out_size; (void)ws_size;
  const float* x = (const float*)d_in[0];
  const float* wq = (const float*)d_in[1];
  const float* wk = (const float*)d_in[2];
  const float* wv = (const float*)d_in[3];
  const float* wo = (const float*)d_in[4];
  const float* fc = (const float*)d_in[5];
  const float* fs = (const float*)d_in[6];
  const float* ck = (const float*)d_in[7];
  const float* cv = (const float*)d_in[8];

  char* ws = (char*)d_ws;
  size_t off = 0;
  auto alloc = [&](size_t bytes) {
    char* p = ws + off;
    off += (bytes + 255) & ~(size_t)255;
    return p;
  };
  half_t* xh    = (half_t*)alloc((size_t)TOK * DIM * 2);       // later qh
  half_t* wqT   = (half_t*)alloc((size_t)DIM * DIM * 2);       // later ah
  half_t* kvT   = (half_t*)alloc((size_t)NKV2 * DIM * 2);
  half_t* woT   = (half_t*)alloc((size_t)DIM * DIM * 2);
  half_t* qf16  = (half_t*)alloc((size_t)TOK * DIM * 2);
  half_t* kvf16 = (half_t*)alloc((size_t)TOK * NKV2 * 2);
  half_t* kh    = (half_t*)alloc((size_t)B_SZ * HKV_N * L_KV * HD_N * 2);
  half_t* vth   = (half_t*)alloc((size_t)B_SZ * HKV_N * HD_N * L_KV * 2);
  half_t* qh    = xh;     // alias: xh dead after kv GEMM
  half_t* ah    = wqT;    // alias: wqT dead after q GEMM

  // 1. merged prep: all 4 weight transposes + x f32->f16, one dispatch
  prep_kernel<<<dim3(26624), dim3(256), 0, stream>>>(x, wq, wk, wv, wo, xh, wqT, kvT, woT);
  // 2. projections: Q via 256^2 (256 blocks = exact round); KV via 128^2 (512 blocks, 2/CU)
  gemm256<half_t><<<dim3((TOK / 256) * (DIM / 256)), dim3(512), 0, stream>>>(xh, wqT, qf16, TOK, DIM, DIM);
  gemm_f16<half_t><<<dim3(NKV2 / 128, TOK / 128), dim3(256), 0, stream>>>(xh, kvT, kvf16, TOK, NKV2, DIM);
  // 3. rope + pack (xh dead after kv GEMM -> qh may overwrite it)
  pack_q_kernel<<<dim3(B_SZ * S_LEN * HQ_N * 64 / 256), dim3(256), 0, stream>>>(qf16, fc, fs, qh);
  pack_k_kernel<<<dim3(B_SZ * L_KV * HKV_N * 64 / 256), dim3(256), 0, stream>>>(kvf16, ck, fc, fs, kh);
  pack_vt_kernel<<<dim3(B_SZ * HKV_N * (L_KV / 128)), dim3(256), 0, stream>>>(kvf16, cv, vth);
  // 4. attention (writes ah = old wqT region); grid (hq, qt, b)
  attn_kernel<<<dim3(HQ_N, S_LEN / 128, B_SZ), dim3(256), 0, stream>>>(qh, kh, vth, ah);
  // 5. output projection
  gemm256<float><<<dim3((TOK / 256) * (DIM / 256)), dim3(512), 0, stream>>>(ah, woT, (float*)d_out, TOK, DIM, DIM);
}

// Round 13
// 625.634 us; speedup vs baseline: 1.0657x; 1.0182x over previous
//
#include <hip/hip_runtime.h>

typedef _Float16 half_t;
typedef _Float16 half8 __attribute__((ext_vector_type(8)));
typedef _Float16 half4v __attribute__((ext_vector_type(4)));
typedef _Float16 half2v __attribute__((ext_vector_type(2)));
typedef float floatx4 __attribute__((ext_vector_type(4)));

#define TOK 4096
#define DIM 4096
#define S_LEN 1024
#define B_SZ 4
#define HQ_N 32
#define HKV_N 8
#define HD_N 128
#define L_KV 2048
#define NKV 1024
#define NKV2 2048
#define QK_SCALE 0.08838834764831845f
#define LOG2E 1.4426950408889634f

__device__ __forceinline__ void gload_lds16(const void* g, void* l) {
  __builtin_amdgcn_global_load_lds(
      (const __attribute__((address_space(1))) unsigned int*)g,
      (__attribute__((address_space(3))) unsigned int*)l, 16, 0, 0);
}

__device__ __forceinline__ float max3f(float a, float b, float c) {
  return fmaxf(fmaxf(a, b), c);   // fuses to v_max3_f32
}

// ---------------- merged prep: 4 weight transposes + x conversion, one dispatch ----------------
__global__ __launch_bounds__(256) void prep_kernel(const float* __restrict__ x,
                                                   const float* __restrict__ wq,
                                                   const float* __restrict__ wk,
                                                   const float* __restrict__ wv,
                                                   const float* __restrict__ wo,
                                                   half_t* __restrict__ xh,
                                                   half_t* __restrict__ wqT,
                                                   half_t* __restrict__ kvT,
                                                   half_t* __restrict__ woT) {
  __shared__ half_t T[64 * 65];
  const int bid = blockIdx.x;
  const int tid = threadIdx.x;
  if (bid >= 10240) {                       // conv_x path
    int t = (bid - 10240) * 256 + tid;
    floatx4 v = *((const floatx4*)x + t);
    half4v o;
    o[0] = (half_t)v[0]; o[1] = (half_t)v[1]; o[2] = (half_t)v[2]; o[3] = (half_t)v[3];
    *((half4v*)xh + t) = o;
    return;
  }
  const float* in; half_t* out; int N; int lb;
  if (bid < 4096)      { in = wq; out = wqT; N = 4096; lb = bid; }
  else if (bid < 5120) { in = wk; out = kvT; N = 1024; lb = bid - 4096; }
  else if (bid < 6144) { in = wv; out = kvT + (size_t)NKV * DIM; N = 1024; lb = bid - 5120; }
  else                 { in = wo; out = woT; N = 4096; lb = bid - 6144; }
  const int nbx = N >> 6;
  const int n0 = (lb % nbx) * 64, k0 = (lb / nbx) * 64;
  #pragma unroll
  for (int i = 0; i < 16; ++i) {
    int idx = i * 256 + tid;
    int r = idx >> 6, c = idx & 63;
    T[c * 65 + r] = (half_t)in[(size_t)(k0 + r) * N + n0 + c];
  }
  __syncthreads();
  #pragma unroll
  for (int i = 0; i < 16; ++i) {
    int idx = i * 256 + tid;
    int rn = idx >> 6, ck = idx & 63;
    out[(size_t)(n0 + rn) * DIM + k0 + ck] = T[rn * 65 + ck];
  }
}

// ---------------- 128^2 GEMM (KV projection): C = A * BT^T ----------------
template <typename OT>
__global__ __launch_bounds__(256) void gemm_f16(const half_t* __restrict__ A,
                                                const half_t* __restrict__ BT,
                                                OT* __restrict__ C,
                                                int M, int N, int K) {
  __shared__ half_t As[128 * 32];
  __shared__ half_t Bs[128 * 32];
  const int tid = threadIdx.x;
  const int lane = tid & 63;
  const int w = tid >> 6;
  const int wr = w >> 1, wc = w & 1;
  const int g = lane >> 4, qr = lane & 15;
  const int m0 = blockIdx.y * 128, n0 = blockIdx.x * 128;
  floatx4 acc[4][4] = {};
  const int chb0 = tid & 192;
  for (int k0 = 0; k0 < K; k0 += 32) {
    #pragma unroll
    for (int i = 0; i < 2; ++i) {
      int chb = chb0 + 256 * i;
      int ch = chb + lane;
      int row = ch >> 2, c8 = ch & 3;
      gload_lds16(A + (size_t)(m0 + row) * K + k0 + c8 * 8, (char*)As + chb * 16);
      gload_lds16(BT + (size_t)(n0 + row) * K + k0 + c8 * 8, (char*)Bs + chb * 16);
    }
    __syncthreads();
    half8 af[4], bf[4];
    const int koff = g * 8;
    #pragma unroll
    for (int m = 0; m < 4; ++m)
      af[m] = *(const half8*)&As[(wr * 64 + m * 16 + qr) * 32 + koff];
    #pragma unroll
    for (int n = 0; n < 4; ++n)
      bf[n] = *(const half8*)&Bs[(wc * 64 + n * 16 + qr) * 32 + koff];
    #pragma unroll
    for (int m = 0; m < 4; ++m)
      #pragma unroll
      for (int n = 0; n < 4; ++n)
        acc[m][n] = __builtin_amdgcn_mfma_f32_16x16x32_f16(af[m], bf[n], acc[m][n], 0, 0, 0);
    __syncthreads();
  }
  #pragma unroll
  for (int m = 0; m < 4; ++m) {
    int rb = m0 + wr * 64 + m * 16 + g * 4;
    #pragma unroll
    for (int n = 0; n < 4; ++n) {
      int col = n0 + wc * 64 + n * 16 + qr;
      #pragma unroll
      for (int r = 0; r < 4; ++r)
        C[(size_t)(rb + r) * N + col] = (OT)acc[m][n][r];
    }
  }
}

// ---------------- 256^2 8-phase GEMM (T1..T5): C[M][N] = A[M][K] * BT[N][K]^T ----------------
// ROPE=true: skip C write; instead apply RoPE+scale*log2e in-register (pair partner
// via shfl_xor(v,1): col parity == qr parity) and write packed qh[b][hq][s][d].
template <typename OT, bool ROPE>
__global__ __launch_bounds__(512) void gemm256(const half_t* __restrict__ A,
                                               const half_t* __restrict__ BT,
                                               OT* __restrict__ C,
                                               const float* __restrict__ fc,
                                               const float* __restrict__ fs,
                                               half_t* __restrict__ qh,
                                               int M, int N, int K) {
  __shared__ __align__(16) char smem[131072];   // A dbuf 64K | B dbuf 64K
  const int tid = threadIdx.x;
  const int lane = tid & 63, w = tid >> 6;
  const int g = lane >> 4, qr = lane & 15;
  const int wm = w >> 2, wn = w & 3;
  const int nbx = N >> 8;
  const int nwg = gridDim.x;
  const int cpx = nwg >> 3;
  const int bid = ((int)blockIdx.x & 7) * cpx + ((int)blockIdx.x >> 3);
  const int bx = bid % nbx, by = bid / nbx;
  const int m0 = by << 8, n0 = bx << 8;
  const int NT = K >> 6;

  const int ch0 = tid, ch1 = tid + 512;
  const int sr0 = ch0 >> 3, sc0 = (ch0 & 7) ^ (sr0 & 7);
  const int sr1 = ch1 >> 3, sc1 = (ch1 & 7) ^ (sr1 & 7);
  const size_t so0 = (size_t)sr0 * K + sc0 * 8;
  const size_t so1 = (size_t)sr1 * K + sc1 * 8;
  const int wb = (w * 64) * 16;
  const half_t* Ab = A + (size_t)m0 * K;
  const half_t* Bb = BT + (size_t)n0 * K;

#define G_STAGE(gsrc, ldst)                                   \
  do {                                                        \
    gload_lds16((gsrc) + so0, (char*)(ldst) + wb);            \
    gload_lds16((gsrc) + so1, (char*)(ldst) + wb + 8192);     \
  } while (0)

#define FRAG(base, row, kb) \
  (*(const half8*)((base) + ((((row) * 128) + (kb)) ^ (((row) & 7) << 4))))

  G_STAGE(Ab, smem);                               // t0.A0
  G_STAGE(Ab + (size_t)128 * K, smem + 16384);     // t0.A1
  G_STAGE(Bb, smem + 65536);                       // t0.B0
  G_STAGE(Bb + (size_t)128 * K, smem + 81920);     // t0.B1
  G_STAGE(Ab + 64, smem + 32768);                  // t1.A0
  G_STAGE(Bb + 64, smem + 98304);                  // t1.B0
  asm volatile("s_waitcnt vmcnt(4)" ::: "memory");
  __builtin_amdgcn_s_barrier();

  floatx4 acc[8][4] = {};
  half8 aF[4][2], bF0[2][2], bF1[2][2];

#define MFMA_Q(mh, nh, BF)                                                     \
  do {                                                                         \
    __builtin_amdgcn_s_setprio(1);                                             \
    _Pragma("unroll") for (int mf = 0; mf < 4; ++mf)                           \
    _Pragma("unroll") for (int nf = 0; nf < 2; ++nf)                           \
    _Pragma("unroll") for (int kk = 0; kk < 2; ++kk)                           \
      acc[(mh)*4 + mf][(nh)*2 + nf] = __builtin_amdgcn_mfma_f32_16x16x32_f16(  \
          aF[mf][kk], BF[nf][kk], acc[(mh)*4 + mf][(nh)*2 + nf], 0, 0, 0);     \
    __builtin_amdgcn_s_setprio(0);                                             \
  } while (0)

  for (int t = 0; t < NT; ++t) {
    const char* Ac = smem + ((t & 1) ? 32768 : 0);
    const char* Bc = smem + 65536 + ((t & 1) ? 32768 : 0);
    char* An = smem + ((t & 1) ? 0 : 32768);
    char* Bn = smem + 65536 + ((t & 1) ? 0 : 32768);
    const int t1 = (t + 1 < NT) ? t + 1 : NT - 1;
    const int t2 = (t + 2 < NT) ? t + 2 : NT - 1;
    // phase 0: read aF(mh=0), bF0; stage (t+1).A1
    #pragma unroll
    for (int mf = 0; mf < 4; ++mf)
      #pragma unroll
      for (int kk = 0; kk < 2; ++kk)
        aF[mf][kk] = FRAG(Ac, wm * 128 + mf * 16 + qr, kk * 64 + g * 16);
    #pragma unroll
    for (int nf = 0; nf < 2; ++nf)
      #pragma unroll
      for (int kk = 0; kk < 2; ++kk)
        bF0[nf][kk] = FRAG(Bc, wn * 64 + nf * 16 + qr, kk * 64 + g * 16);
    G_STAGE(Ab + (size_t)128 * K + t1 * 64, An + 16384);
    __builtin_amdgcn_s_barrier();
    asm volatile("s_waitcnt lgkmcnt(0)" ::: "memory");
    MFMA_Q(0, 0, bF0);
    __builtin_amdgcn_s_barrier();
    // phase 1: read bF1; stage (t+1).B1
    #pragma unroll
    for (int nf = 0; nf < 2; ++nf)
      #pragma unroll
      for (int kk = 0; kk < 2; ++kk)
        bF1[nf][kk] = FRAG(Bc, wn * 64 + 32 + nf * 16 + qr, kk * 64 + g * 16);
    G_STAGE(Bb + (size_t)128 * K + t1 * 64, Bn + 16384);
    __builtin_amdgcn_s_barrier();
    asm volatile("s_waitcnt lgkmcnt(0)" ::: "memory");
    MFMA_Q(0, 1, bF1);
    __builtin_amdgcn_s_barrier();
    // phase 2: read aF(mh=1)
    #pragma unroll
    for (int mf = 0; mf < 4; ++mf)
      #pragma unroll
      for (int kk = 0; kk < 2; ++kk)
        aF[mf][kk] = FRAG(Ac, wm * 128 + 64 + mf * 16 + qr, kk * 64 + g * 16);
    __builtin_amdgcn_s_barrier();
    asm volatile("s_waitcnt lgkmcnt(0)" ::: "memory");
    MFMA_Q(1, 1, bF1);
    __builtin_amdgcn_s_barrier();
    // phase 3: stage (t+2).A0/B0 into cur-parity buf; counted vmcnt
    G_STAGE(Ab + (size_t)t2 * 64, (char*)Ac);
    G_STAGE(Bb + (size_t)t2 * 64, (char*)Bc);
    __builtin_amdgcn_s_barrier();
    MFMA_Q(1, 0, bF0);
    asm volatile("s_waitcnt vmcnt(4)" ::: "memory");
    __builtin_amdgcn_s_barrier();
  }
  // epilogue
  #pragma unroll
  for (int mh = 0; mh < 2; ++mh)
    #pragma unroll
    for (int mf = 0; mf < 4; ++mf) {
      const int rb = m0 + wm * 128 + mh * 64 + mf * 16 + g * 4;
      #pragma unroll
      for (int nh = 0; nh < 2; ++nh)
        #pragma unroll
        for (int nf = 0; nf < 2; ++nf) {
          const int col = n0 + wn * 64 + nh * 32 + nf * 16 + qr;
          floatx4 v = acc[mh * 4 + mf][nh * 2 + nf];
          if constexpr (ROPE) {
            const float QS2 = QK_SCALE * LOG2E;
            const int d = col & 127, hqh = col >> 7, j = d >> 1;
            #pragma unroll
            for (int r = 0; r < 4; ++r) {
              float pv = __shfl_xor(v[r], 1, 64);
              const int tokr = rb + r;
              const int s = tokr & 1023, bb = tokr >> 10;
              float c = fc[s * 64 + j], sn = fs[s * 64 + j];
              // even col (qr even): xr=v, xi=pv -> v*c - pv*sn
              // odd  col (qr odd):  xr=pv, xi=v -> pv*sn + v*c
              float outv = (qr & 1) ? (v[r] * c + pv * sn) : (v[r] * c - pv * sn);
              qh[(((size_t)(bb * HQ_N + hqh)) * S_LEN + s) * HD_N + d] =
                  (half_t)(outv * QS2);
            }
          } else {
            #pragma unroll
            for (int r = 0; r < 4; ++r)
              C[(size_t)(rb + r) * N + col] = (OT)v[r];
          }
        }
    }
#undef G_STAGE
#undef FRAG
#undef MFMA_Q
}

// ---------------- pack keys from fused kv: cache + rope(new) -> [B][HKV][L][HD] f16 ----------------
__global__ __launch_bounds__(256) void pack_k_kernel(const half_t* __restrict__ kvf,
                                                     const float* __restrict__ cache_k,
                                                     const float* __restrict__ cosT,
                                                     const float* __restrict__ sinT,
                                                     half_t* __restrict__ kh) {
  int t = blockIdx.x * 256 + threadIdx.x;
  int j = t & 63;
  int h = (t >> 6) & 7;
  int pos = (t >> 9) & 2047;
  int b = t >> 20;
  float xr, xi;
  if (pos < 1024) {
    const float* src = cache_k + ((size_t)(b * L_KV + pos) * HKV_N + h) * HD_N + 2 * j;
    xr = src[0]; xi = src[1];
  } else {
    int s = pos - 1024;
    const half_t* src = kvf + (size_t)(b * S_LEN + s) * NKV2 + h * HD_N + 2 * j;
    float r0 = (float)src[0], i0 = (float)src[1];
    float c = cosT[s * 64 + j], sn = sinT[s * 64 + j];
    xr = r0 * c - i0 * sn;
    xi = r0 * sn + i0 * c;
  }
  half2v o; o[0] = (half_t)xr; o[1] = (half_t)xi;
  *(half2v*)(kh + ((size_t)(b * HKV_N + h) * L_KV + pos) * HD_N + 2 * j) = o;
}

// ---------------- pack values transposed from fused kv: -> [B][HKV][HD][L] f16 ----------------
__global__ __launch_bounds__(256) void pack_vt_kernel(const half_t* __restrict__ kvf,
                                                      const float* __restrict__ cache_v,
                                                      half_t* __restrict__ vt) {
  __shared__ half_t T[128 * 129];
  const int tid = threadIdx.x;
  const int blk = blockIdx.x;
  const int pt = blk & 15;
  const int h = (blk >> 4) & 7;
  const int b = blk >> 7;
  const int p0 = pt * 128;
  #pragma unroll
  for (int i = 0; i < 64; ++i) {
    int idx = i * 256 + tid;
    int p = idx >> 7, d = idx & 127;
    int pos = p0 + p;
    float v;
    if (pos < 1024)
      v = cache_v[((size_t)(b * L_KV + pos) * HKV_N + h) * HD_N + d];
    else
      v = (float)kvf[(size_t)(b * S_LEN + (pos - 1024)) * NKV2 + NKV + h * HD_N + d];
    T[d * 129 + p] = (half_t)v;
  }
  __syncthreads();
  #pragma unroll
  for (int i = 0; i < 64; ++i) {
    int idx = i * 256 + tid;
    int d = idx >> 7, p = idx & 127;
    vt[((size_t)(b * HKV_N + h) * HD_N + d) * L_KV + p0 + p] = T[d * 129 + p];
  }
}

// ---------------- flash attention: shared K/V fragments, conflict-free P layout ----------------
__global__ __launch_bounds__(256, 2) void attn_kernel(const half_t* __restrict__ qh,
                                                      const half_t* __restrict__ kh,
                                                      const half_t* __restrict__ vt,
                                                      half_t* __restrict__ ah) {
  __shared__ __align__(16) char smem[73728];
  const int tid = threadIdx.x;
  const int lane = tid & 63, w = tid >> 6;
  const int g = lane >> 4, qr = lane & 15;
  const int hq = blockIdx.x, qt = blockIdx.y, b = blockIdx.z;
  const int hkv = hq >> 2;
  const half_t* qbase =
      qh + ((size_t)((b * HQ_N + hq) * S_LEN) + qt * 128 + w * 16 + qr) * HD_N;
  half8 qfA[4], qfB[4];
  #pragma unroll
  for (int c = 0; c < 4; ++c) {
    qfA[c] = *(const half8*)(qbase + g * 8 + c * 32);
    qfB[c] = *(const half8*)(qbase + (size_t)64 * HD_N + g * 8 + c * 32);
  }
  floatx4 accA[8] = {}, accB[8] = {};
  float mA = -1e30f, lA = 0.f, mB = -1e30f, lB = 0.f;
  const half_t* kg = kh + (size_t)(b * HKV_N + hkv) * L_KV * HD_N;
  const half_t* vg = vt + (size_t)(b * HKV_N + hkv) * HD_N * L_KV;

  const int sw = (qr & 7) << 4;
  const char* kqkP[4];
  #pragma unroll
  for (int c = 0; c < 4; ++c) kqkP[c] = smem + qr * 256 + ((g * 16 + c * 64) ^ sw);
  const char* vP[2];
  #pragma unroll
  for (int kc = 0; kc < 2; ++kc)
    vP[kc] = smem + 32768 + qr * 128 + ((kc * 64 + g * 16) ^ sw);
  char* pB = smem + 65536 + w * 2048 + qr * 128;
  char* pwQ[4];
  #pragma unroll
  for (int ts = 0; ts < 4; ++ts) pwQ[ts] = pB + ((ts * 32 + g * 8) ^ sw);
  const char* prR[2];
  #pragma unroll
  for (int kc = 0; kc < 2; ++kc) prR[kc] = pB + ((kc * 64 + g * 16) ^ sw);

  const int r0 = tid >> 4;
  const int c8k = (tid & 15) ^ (r0 & 7);
  const half_t* kp[4];
  #pragma unroll
  for (int j = 0; j < 4; ++j) kp[j] = kg + (size_t)(r0 + 16 * j) * HD_N + c8k * 8;
  const int d0v = tid >> 3;
  const int p8v = (tid & 7) ^ (d0v & 7);
  const half_t* vp[4];
  #pragma unroll
  for (int j = 0; j < 4; ++j) vp[j] = vg + (size_t)(d0v + 32 * j) * L_KV + p8v * 8;
  const int ldsb = (tid & 192) * 16;

#define ISSUE_STAGE(NKB)                                                     \
  do {                                                                       \
    _Pragma("unroll") for (int j2 = 0; j2 < 4; ++j2)                         \
      gload_lds16(kp[j2], smem + (NKB) + ldsb + j2 * 4096);                  \
    _Pragma("unroll") for (int j2 = 0; j2 < 4; ++j2)                         \
      gload_lds16(vp[j2], smem + 32768 + (NKB) + ldsb + j2 * 4096);          \
    _Pragma("unroll") for (int j2 = 0; j2 < 4; ++j2) {                       \
      kp[j2] += 8192; vp[j2] += 64;                                          \
    }                                                                        \
  } while (0)

#define QKT2(KB)                                                               \
  do {                                                                         \
    __builtin_amdgcn_s_setprio(1);                                             \
    _Pragma("unroll") for (int ts = 0; ts < 4; ++ts) {                         \
      floatx4 tqA = {0.f, 0.f, 0.f, 0.f}, tqB = {0.f, 0.f, 0.f, 0.f};          \
      _Pragma("unroll") for (int c = 0; c < 4; ++c) {                          \
        half8 kfr = *(const half8*)(kqkP[c] + (KB) + ts * 4096);               \
        tqA = __builtin_amdgcn_mfma_f32_16x16x32_f16(kfr, qfA[c], tqA, 0,0,0); \
        tqB = __builtin_amdgcn_mfma_f32_16x16x32_f16(kfr, qfB[c], tqB, 0,0,0); \
      }                                                                        \
      scA[ts*4+0]=tqA[0]; scA[ts*4+1]=tqA[1];                                  \
      scA[ts*4+2]=tqA[2]; scA[ts*4+3]=tqA[3];                                  \
      scB[ts*4+0]=tqB[0]; scB[ts*4+1]=tqB[1];                                  \
      scB[ts*4+2]=tqB[2]; scB[ts*4+3]=tqB[3];                                  \
    }                                                                          \
    __builtin_amdgcn_s_setprio(0);                                             \
  } while (0)

#define SOFTMAX(SC, ACC, MR, LR, PF)                                           \
  do {                                                                         \
    float pmax = fmaxf(                                                        \
        max3f(max3f(SC[0], SC[1], SC[2]), max3f(SC[3], SC[4], SC[5]),          \
              max3f(SC[6], SC[7], SC[8])),                                     \
        max3f(max3f(SC[9], SC[10], SC[11]), max3f(SC[12], SC[13], SC[14]),     \
              SC[15]));                                                        \
    pmax = fmaxf(pmax, __shfl_xor(pmax, 16, 64));                              \
    pmax = fmaxf(pmax, __shfl_xor(pmax, 32, 64));                              \
    const bool skip = __all(pmax - MR <= 8.f);                                 \
    const float mnew = skip ? MR : fmaxf(MR, pmax);                            \
    float rs = 0.f;                                                            \
    _Pragma("unroll") for (int j = 0; j < 16; ++j) {                           \
      float p;                                                                 \
      asm("v_exp_f32 %0, %1" : "=v"(p) : "v"(SC[j] - mnew));                   \
      SC[j] = p; rs += p;                                                      \
    }                                                                          \
    rs += __shfl_xor(rs, 16, 64);                                              \
    rs += __shfl_xor(rs, 32, 64);                                              \
    if (skip) {                                                                \
      LR += rs;                                                                \
    } else {                                                                   \
      float scl;                                                               \
      asm("v_exp_f32 %0, %1" : "=v"(scl) : "v"(MR - mnew));                    \
      LR = LR * scl + rs;                                                      \
      float f0 = __shfl(scl, g * 4 + 0, 64), f1 = __shfl(scl, g * 4 + 1, 64);  \
      float f2 = __shfl(scl, g * 4 + 2, 64), f3 = __shfl(scl, g * 4 + 3, 64);  \
      _Pragma("unroll") for (int n = 0; n < 8; ++n) {                          \
        ACC[n][0] *= f0; ACC[n][1] *= f1; ACC[n][2] *= f2; ACC[n][3] *= f3;    \
      }                                                                        \
      MR = mnew;                                                               \
    }                                                                          \
    _Pragma("unroll") for (int ts = 0; ts < 4; ++ts) {                         \
      half2v lo = __builtin_bit_cast(                                          \
          half2v, __builtin_amdgcn_cvt_pkrtz(SC[ts * 4 + 0], SC[ts * 4 + 1])); \
      half2v hi = __builtin_bit_cast(                                          \
          half2v, __builtin_amdgcn_cvt_pkrtz(SC[ts * 4 + 2], SC[ts * 4 + 3])); \
      *(half4v*)(pwQ[ts]) = __builtin_shufflevector(lo, hi, 0, 1, 2, 3);       \
    }                                                                          \
    PF[0] = *(const half8*)(prR[0]);                                           \
    PF[1] = *(const half8*)(prR[1]);                                           \
  } while (0)

#define PV2(KB)                                                                \
  do {                                                                         \
    __builtin_amdgcn_s_setprio(1);                                             \
    _Pragma("unroll") for (int kc = 0; kc < 2; ++kc)                           \
      _Pragma("unroll") for (int n = 0; n < 8; ++n) {                          \
        half8 vfr = *(const half8*)(vP[kc] + (KB) + n * 2048);                 \
        accA[n] = __builtin_amdgcn_mfma_f32_16x16x32_f16(pfA[kc], vfr,         \
                                                         accA[n], 0, 0, 0);   \
        accB[n] = __builtin_amdgcn_mfma_f32_16x16x32_f16(pfB[kc], vfr,         \
                                                         accB[n], 0, 0, 0);   \
      }                                                                        \
    __builtin_amdgcn_s_setprio(0);                                             \
  } while (0)

#define COMPUTE2(KB)                          \
  do {                                        \
    float scA[16], scB[16];                   \
    half8 pfA[2], pfB[2];                     \
    QKT2(KB);                                 \
    SOFTMAX(scA, accA, mA, lA, pfA);          \
    SOFTMAX(scB, accB, mB, lB, pfB);          \
    PV2(KB);                                  \
  } while (0)

#define ENDBAR                                          \
  do {                                                  \
    asm volatile("s_waitcnt vmcnt(0)" ::: "memory");    \
    __builtin_amdgcn_s_barrier();                       \
  } while (0)

  ISSUE_STAGE(0);
  ENDBAR;
  for (int it = 0; it < 15; ++it) {
    ISSUE_STAGE(16384); COMPUTE2(0);     ENDBAR;
    ISSUE_STAGE(0);     COMPUTE2(16384); ENDBAR;
  }
  ISSUE_STAGE(16384); COMPUTE2(0); ENDBAR;
  COMPUTE2(16384);

#define WRITE_OUT(ACC, LR, SOFF)                                            \
  do {                                                                      \
    float il0 = 1.f / __shfl(LR, g * 4 + 0, 64);                            \
    float il1 = 1.f / __shfl(LR, g * 4 + 1, 64);                            \
    float il2 = 1.f / __shfl(LR, g * 4 + 2, 64);                            \
    float il3 = 1.f / __shfl(LR, g * 4 + 3, 64);                            \
    const int tokb = b * S_LEN + qt * 128 + (SOFF) + w * 16 + g * 4;        \
    _Pragma("unroll") for (int n = 0; n < 8; ++n) {                         \
      const int col = hq * HD_N + n * 16 + qr;                              \
      ah[(size_t)(tokb + 0) * DIM + col] = (half_t)(ACC[n][0] * il0);       \
      ah[(size_t)(tokb + 1) * DIM + col] = (half_t)(ACC[n][1] * il1);       \
      ah[(size_t)(tokb + 2) * DIM + col] = (half_t)(ACC[n][2] * il2);       \
      ah[(size_t)(tokb + 3) * DIM + col] = (half_t)(ACC[n][3] * il3);       \
    }                                                                       \
  } while (0)

  WRITE_OUT(accA, lA, 0);
  WRITE_OUT(accB, lB, 64);
#undef ISSUE_STAGE
#undef QKT2
#undef SOFTMAX
#undef PV2
#undef COMPUTE2
#undef ENDBAR
#undef WRITE_OUT
}

extern "C" void kernel_launch(void* const* d_in, const int* in_sizes, int n_in,
                              void* d_out, int out_size, void* d_ws, size_t ws_size,
                              hipStream_t stream) {
  (void)in_sizes; (void)n_in; (void)out_size; (void)ws_size;
  const float* x = (const float*)d_in[0];
  const float* wq = (const float*)d_in[1];
  const float* wk = (const float*)d_in[2];
  const float* wv = (const float*)d_in[3];
  const float* wo = (const float*)d_in[4];
  const float* fc = (const float*)d_in[5];
  const float* fs = (const float*)d_in[6];
  const float* ck = (const float*)d_in[7];
  const float* cv = (const float*)d_in[8];

  char* ws = (char*)d_ws;
  size_t off = 0;
  auto alloc = [&](size_t bytes) {
    char* p = ws + off;
    off += (bytes + 255) & ~(size_t)255;
    return p;
  };
  half_t* xh    = (half_t*)alloc((size_t)TOK * DIM * 2);
  half_t* wqT   = (half_t*)alloc((size_t)DIM * DIM * 2);       // later ah
  half_t* kvT   = (half_t*)alloc((size_t)NKV2 * DIM * 2);
  half_t* woT   = (half_t*)alloc((size_t)DIM * DIM * 2);
  half_t* qh    = (half_t*)alloc((size_t)B_SZ * HQ_N * S_LEN * HD_N * 2);
  half_t* kvf16 = (half_t*)alloc((size_t)TOK * NKV2 * 2);
  half_t* kh    = (half_t*)alloc((size_t)B_SZ * HKV_N * L_KV * HD_N * 2);
  half_t* vth   = (half_t*)alloc((size_t)B_SZ * HKV_N * HD_N * L_KV * 2);
  half_t* ah    = wqT;    // alias: wqT dead after q GEMM

  // 1. merged prep: all 4 weight transposes + x f32->f16, one dispatch
  prep_kernel<<<dim3(26624), dim3(256), 0, stream>>>(x, wq, wk, wv, wo, xh, wqT, kvT, woT);
  // 2. Q projection with fused RoPE+pack epilogue (writes qh directly)
  gemm256<half_t, true><<<dim3((TOK / 256) * (DIM / 256)), dim3(512), 0, stream>>>(
      xh, wqT, (half_t*)nullptr, fc, fs, qh, TOK, DIM, DIM);
  // 3. KV projection via 128^2 (512 blocks, 2/CU)
  gemm_f16<half_t><<<dim3(NKV2 / 128, TOK / 128), dim3(256), 0, stream>>>(xh, kvT, kvf16, TOK, NKV2, DIM);
  // 4. k/v packs
  pack_k_kernel<<<dim3(B_SZ * L_KV * HKV_N * 64 / 256), dim3(256), 0, stream>>>(kvf16, ck, fc, fs, kh);
  pack_vt_kernel<<<dim3(B_SZ * HKV_N * (L_KV / 128)), dim3(256), 0, stream>>>(kvf16, cv, vth);
  // 5. attention (writes ah = old wqT region); grid (hq, qt, b)
  attn_kernel<<<dim3(HQ_N, S_LEN / 128, B_SZ), dim3(256), 0, stream>>>(qh, kh, vth, ah);
  // 6. output projection
  gemm256<float, false><<<dim3((TOK / 256) * (DIM / 256)), dim3(512), 0, stream>>>(
      ah, woT, (float*)d_out, nullptr, nullptr, nullptr, TOK, DIM, DIM);
}